// Round 1
// baseline (9487.603 us; speedup 1.0000x reference)
//
#include <hip/hip_runtime.h>

#define F 128
#define BN_EPS 1e-5f
#define AT_S 65   // A-tile LDS stride: 64 k + 1 pad -> conflict-free scalar reads

// ---------------- scatter: z0[dst][:] += h[src][:], 32 lanes per edge ----------------
__global__ __launch_bounds__(256) void k_scatter(
    const float* __restrict__ h, const int* __restrict__ src,
    const int* __restrict__ dst, float* z0, int E)
{
    int e = blockIdx.x * 8 + (threadIdx.x >> 5);
    if (e >= E) return;
    int lane = threadIdx.x & 31;
    int s = src[e], d = dst[e];
    float4 v = *((const float4*)(h + (size_t)s * F) + lane);
    float* p = z0 + (size_t)d * F + lane * 4;
    atomicAdd(p + 0, v.x);
    atomicAdd(p + 1, v.y);
    atomicAdd(p + 2, v.z);
    atomicAdd(p + 3, v.w);
}

// ---------------- GEMM: C = relu(A @ W + bias), optional BN-stats accumulation ----------------
// A:[N,128] row-major, W:[128,128] row-major (k,col), C:[N,128].
// Tile: 128 rows x 128 cols per block, 256 threads, 8x8 register tile/thread.
// LDS: W chunk [64][128] (32KB) + A tile [128][65] (32.5KB) -> 2 blocks/CU.
__global__ __launch_bounds__(256, 2) void k_gemm(
    const float* __restrict__ A, const float* __restrict__ W,
    const float* __restrict__ bias, float* __restrict__ C,
    int N, float* stats /* null, or [0:128]=col sums, [128:256]=col sumsq */)
{
    __shared__ float Wl[64 * F];
    __shared__ float At[F * AT_S];
    const int t = threadIdx.x;
    const int row0 = blockIdx.x << 7;
    const int tr = t >> 4, tc = t & 15;
    const int r0 = tr << 3, c0 = tc << 3;

    float acc[8][8];
#pragma unroll
    for (int i = 0; i < 8; ++i)
#pragma unroll
        for (int j = 0; j < 8; ++j) acc[i][j] = 0.f;

    for (int kb = 0; kb < 2; ++kb) {
        if (kb) __syncthreads();
        const float* Wsrc = W + (size_t)(kb << 6) * F;
#pragma unroll
        for (int i = 0; i < 8; ++i) {
            int idx = t + (i << 8);                 // 0..2047 float4s = 64x128 floats
            ((float4*)Wl)[idx] = ((const float4*)Wsrc)[idx];
        }
#pragma unroll
        for (int i = 0; i < 8; ++i) {
            int idx = t + (i << 8);                 // 0..2047
            int row = idx >> 4;                     // 0..127
            int k4  = (idx & 15) << 2;              // 0..60
            float4 v = make_float4(0.f, 0.f, 0.f, 0.f);
            int gr = row0 + row;
            if (gr < N) v = *(const float4*)(A + (size_t)gr * F + (kb << 6) + k4);
            float* w = At + row * AT_S + k4;
            w[0] = v.x; w[1] = v.y; w[2] = v.z; w[3] = v.w;
        }
        __syncthreads();
#pragma unroll 4
        for (int k = 0; k < 64; ++k) {
            float a[8], b[8];
#pragma unroll
            for (int i = 0; i < 8; ++i) a[i] = At[(r0 + i) * AT_S + k];
            *(float4*)&b[0] = *(float4*)&Wl[k * F + c0];
            *(float4*)&b[4] = *(float4*)&Wl[k * F + c0 + 4];
#pragma unroll
            for (int i = 0; i < 8; ++i)
#pragma unroll
                for (int j = 0; j < 8; ++j)
                    acc[i][j] = fmaf(a[i], b[j], acc[i][j]);
        }
    }

    float bv[8];
    *(float4*)&bv[0] = *(const float4*)(bias + c0);
    *(float4*)&bv[4] = *(const float4*)(bias + c0 + 4);

    float s[8], q[8];
#pragma unroll
    for (int j = 0; j < 8; ++j) { s[j] = 0.f; q[j] = 0.f; }

#pragma unroll
    for (int i = 0; i < 8; ++i) {
        int gr = row0 + r0 + i;
        if (gr < N) {
            float vv[8];
#pragma unroll
            for (int j = 0; j < 8; ++j) {
                float u = acc[i][j] + bv[j];
                u = u > 0.f ? u : 0.f;
                vv[j] = u; s[j] += u; q[j] += u * u;
            }
            *(float4*)(C + (size_t)gr * F + c0)     = *(float4*)&vv[0];
            *(float4*)(C + (size_t)gr * F + c0 + 4) = *(float4*)&vv[4];
        }
    }

    if (stats) {
        __syncthreads();                 // done reading At; reuse as reduction scratch
        float* cs = At;
        float* cq = At + F;
        if (t < F) { cs[t] = 0.f; cq[t] = 0.f; }
        __syncthreads();
#pragma unroll
        for (int j = 0; j < 8; ++j) {
            atomicAdd(&cs[c0 + j], s[j]);
            atomicAdd(&cq[c0 + j], q[j]);
        }
        __syncthreads();
        if (t < F) {
            atomicAdd(&stats[t],     cs[t]);
            atomicAdd(&stats[F + t], cq[t]);
        }
    }
}

// ---------------- finalize BN coefficients: zhat = a*z + c ----------------
__global__ void k_bn_coef(const float* __restrict__ stats,
                          const float* __restrict__ gamma,
                          const float* __restrict__ beta,
                          float invN, float* __restrict__ coef)
{
    int f = threadIdx.x;
    float mean = stats[f] * invN;
    float var  = stats[F + f] * invN - mean * mean;
    float a = gamma[f] * rsqrtf(var + BN_EPS);
    coef[f]     = a;
    coef[F + f] = beta[f] - mean * a;
}

// ---------------- BN apply (in-place) + global add pool into out (stride 384) ----------------
__global__ __launch_bounds__(256) void k_bn_pool(
    float* zh, const float* __restrict__ coef,
    const int* __restrict__ batch, float* outL, int N)
{
    int idx = blockIdx.x * 256 + threadIdx.x;   // one float4 per thread
    int n = idx >> 5;
    if (n >= N) return;
    int f = (idx & 31) << 2;
    float4 v = *(const float4*)(zh + (size_t)n * F + f);
    float4 a = *(const float4*)(coef + f);
    float4 c = *(const float4*)(coef + F + f);
    float4 y;
    y.x = fmaf(v.x, a.x, c.x);
    y.y = fmaf(v.y, a.y, c.y);
    y.z = fmaf(v.z, a.z, c.z);
    y.w = fmaf(v.w, a.w, c.w);
    *(float4*)(zh + (size_t)n * F + f) = y;     // becomes h for next layer
    int g = batch[n];
    float* p = outL + (size_t)g * 384 + f;
    atomicAdd(p + 0, y.x);
    atomicAdd(p + 1, y.y);
    atomicAdd(p + 2, y.z);
    atomicAdd(p + 3, y.w);
}

extern "C" void kernel_launch(void* const* d_in, const int* in_sizes, int n_in,
                              void* d_out, int out_size, void* d_ws, size_t ws_size,
                              hipStream_t stream)
{
    const float* x     = (const float*)d_in[0];
    const int*   ei    = (const int*)  d_in[1];
    const int*   batch = (const int*)  d_in[2];
    const float* W1    = (const float*)d_in[3];
    const float* b1    = (const float*)d_in[4];
    const float* W2    = (const float*)d_in[5];
    const float* b2    = (const float*)d_in[6];
    const float* gamma = (const float*)d_in[7];
    const float* beta  = (const float*)d_in[8];

    const int N = in_sizes[0] / F;      // 100000
    const int E = in_sizes[1] / 2;      // 1600000
    const int* src = ei;
    const int* dst = ei + E;
    float* out = (float*)d_out;

    const size_t NF = (size_t)N * F;
    float* B0    = (float*)d_ws;        // N*F
    float* B1    = B0 + NF;             // N*F
    float* stats = B1 + NF;             // 3 * 256 (sum, sumsq per layer)
    float* coef  = stats + 3 * 256;     // 3 * 256 (a, c per layer)

    hipMemsetAsync(out, 0, (size_t)out_size * sizeof(float), stream);
    hipMemsetAsync(stats, 0, 3 * 256 * sizeof(float), stream);

    const float invN = 1.0f / (float)N;
    const int gemm_grid = (N + 127) / 128;
    const int pool_grid = (int)((NF / 4 + 255) / 256);

    for (int L = 0; L < 3; ++L) {
        // buffer rotation: h dead after scatter; GEMM2 writes over z0; BN in-place = h_next
        const float* h  = (L == 0) ? x : ((L == 1) ? B0 : B1);
        float* z0 = (L == 1) ? B1 : B0;
        float* tb = (L == 1) ? B0 : B1;

        hipMemcpyAsync(z0, h, NF * sizeof(float), hipMemcpyDeviceToDevice, stream); // z0 = h
        k_scatter<<<(E + 7) / 8, 256, 0, stream>>>(h, src, dst, z0, E);             // z0 += agg
        k_gemm<<<gemm_grid, 256, 0, stream>>>(z0, W1 + (size_t)L * F * F, b1 + L * F,
                                              tb, N, nullptr);                      // t = relu(z0@W1+b1)
        k_gemm<<<gemm_grid, 256, 0, stream>>>(tb, W2 + (size_t)L * F * F, b2 + L * F,
                                              z0, N, stats + L * 256);              // z = relu(t@W2+b2) + stats
        k_bn_coef<<<1, F, 0, stream>>>(stats + L * 256, gamma + L * F, beta + L * F,
                                       invN, coef + L * 256);
        k_bn_pool<<<pool_grid, 256, 0, stream>>>(z0, coef + L * 256, batch,
                                                 out + L * F, N);                   // BN + pool
    }
}

// Round 2
// 1932.297 us; speedup vs baseline: 4.9100x; 4.9100x over previous
//
#include <hip/hip_runtime.h>

#define F 128
#define BN_EPS 1e-5f
#define AT_S 65   // A-tile LDS stride: 64 k + 1 pad -> conflict-free scalar reads

// ================= CSR build (counting sort of edges by dst) =================

__global__ __launch_bounds__(256) void k_hist(const int* __restrict__ dst,
                                              int* __restrict__ deg, int E)
{
    int e = blockIdx.x * 256 + threadIdx.x;
    if (e < E) atomicAdd(&deg[dst[e]], 1);
}

// block-local exclusive scan over 1024-elem chunks; block totals -> bsum
__global__ __launch_bounds__(256) void k_scan1(const int* __restrict__ deg,
                                               int* __restrict__ rowptr,
                                               int* __restrict__ bsum, int N)
{
    __shared__ int lds[256];
    const int t = threadIdx.x;
    const int base = blockIdx.x * 1024 + t * 4;
    int4 v = make_int4(0, 0, 0, 0);
    if (base + 3 < N) v = *(const int4*)(deg + base);
    else {
        int* vv = (int*)&v;
        for (int i = 0; i < 4; ++i) vv[i] = (base + i < N) ? deg[base + i] : 0;
    }
    int s = v.x + v.y + v.z + v.w;
    lds[t] = s;
    __syncthreads();
    for (int off = 1; off < 256; off <<= 1) {
        int u = (t >= off) ? lds[t - off] : 0;
        __syncthreads();
        if (t >= off) lds[t] += u;
        __syncthreads();
    }
    int excl = lds[t] - s;
    if (t == 255) bsum[blockIdx.x] = lds[255];
    int4 o;
    o.x = excl; o.y = o.x + v.x; o.z = o.y + v.y; o.w = o.z + v.z;
    if (base + 3 < N) *(int4*)(rowptr + base) = o;
    else {
        int* oo = (int*)&o;
        for (int i = 0; i < 4; ++i) if (base + i < N) rowptr[base + i] = oo[i];
    }
}

// single-block exclusive scan of block sums (NBLK <= 256)
__global__ __launch_bounds__(256) void k_scan2(int* __restrict__ bsum, int nblk)
{
    __shared__ int lds[256];
    const int t = threadIdx.x;
    int s = (t < nblk) ? bsum[t] : 0;
    lds[t] = s;
    __syncthreads();
    for (int off = 1; off < 256; off <<= 1) {
        int u = (t >= off) ? lds[t - off] : 0;
        __syncthreads();
        if (t >= off) lds[t] += u;
        __syncthreads();
    }
    if (t < nblk) bsum[t] = lds[t] - s;
}

__global__ __launch_bounds__(256) void k_scan3(int* __restrict__ rowptr,
                                               int* __restrict__ cursor,
                                               const int* __restrict__ bsum,
                                               int N, int E)
{
    int i = blockIdx.x * 1024 + threadIdx.x * 4;
    int off = bsum[blockIdx.x];
    for (int k = 0; k < 4; ++k) {
        int idx = i + k;
        if (idx < N) {
            int v = rowptr[idx] + off;
            rowptr[idx] = v;
            cursor[idx] = v;
        }
    }
    if (blockIdx.x == 0 && threadIdx.x == 0) rowptr[N] = E;
}

__global__ __launch_bounds__(256) void k_fill(const int* __restrict__ src,
                                              const int* __restrict__ dst,
                                              int* __restrict__ cursor,
                                              int* __restrict__ esrc, int E)
{
    int e = blockIdx.x * 256 + threadIdx.x;
    if (e < E) {
        int pos = atomicAdd(&cursor[dst[e]], 1);
        esrc[pos] = src[e];
    }
}

// ============ aggregate: z0[n] = h[n] + sum_{j in adj(n)} h[src_j] ============
// one 64-lane wave per node; lane holds float2 (128 feats); edge ids via scalar loads
__global__ __launch_bounds__(256) void k_agg(const float* __restrict__ h,
                                             const int* __restrict__ rowptr,
                                             const int* __restrict__ esrc,
                                             float* __restrict__ z0, int N)
{
    int n = (blockIdx.x * 256 + threadIdx.x) >> 6;
    if (n >= N) return;
    n = __builtin_amdgcn_readfirstlane(n);        // wave-uniform -> scalar loads below
    const int lane = threadIdx.x & 63;
    const int beg = rowptr[n], end = rowptr[n + 1];
    const float2* h2 = (const float2*)h;

    float2 a0 = h2[(size_t)n * 64 + lane];
    float2 a1 = make_float2(0.f, 0.f);
    int j = beg;
    for (; j + 2 <= end; j += 2) {
        int s0 = esrc[j], s1 = esrc[j + 1];
        float2 v0 = h2[(size_t)s0 * 64 + lane];
        float2 v1 = h2[(size_t)s1 * 64 + lane];
        a0.x += v0.x; a0.y += v0.y;
        a1.x += v1.x; a1.y += v1.y;
    }
    if (j < end) {
        int s = esrc[j];
        float2 v = h2[(size_t)s * 64 + lane];
        a0.x += v.x; a0.y += v.y;
    }
    a0.x += a1.x; a0.y += a1.y;
    ((float2*)z0)[(size_t)n * 64 + lane] = a0;
}

// ---------------- GEMM: C = relu(A @ W + bias), optional BN-stats accumulation ----------------
__global__ __launch_bounds__(256, 2) void k_gemm(
    const float* __restrict__ A, const float* __restrict__ W,
    const float* __restrict__ bias, float* __restrict__ C,
    int N, float* stats /* null, or [0:128]=col sums, [128:256]=col sumsq */)
{
    __shared__ float Wl[64 * F];
    __shared__ float At[F * AT_S];
    const int t = threadIdx.x;
    const int row0 = blockIdx.x << 7;
    const int tr = t >> 4, tc = t & 15;
    const int r0 = tr << 3, c0 = tc << 3;

    float acc[8][8];
#pragma unroll
    for (int i = 0; i < 8; ++i)
#pragma unroll
        for (int j = 0; j < 8; ++j) acc[i][j] = 0.f;

    for (int kb = 0; kb < 2; ++kb) {
        if (kb) __syncthreads();
        const float* Wsrc = W + (size_t)(kb << 6) * F;
#pragma unroll
        for (int i = 0; i < 8; ++i) {
            int idx = t + (i << 8);
            ((float4*)Wl)[idx] = ((const float4*)Wsrc)[idx];
        }
#pragma unroll
        for (int i = 0; i < 8; ++i) {
            int idx = t + (i << 8);
            int row = idx >> 4;
            int k4  = (idx & 15) << 2;
            float4 v = make_float4(0.f, 0.f, 0.f, 0.f);
            int gr = row0 + row;
            if (gr < N) v = *(const float4*)(A + (size_t)gr * F + (kb << 6) + k4);
            float* w = At + row * AT_S + k4;
            w[0] = v.x; w[1] = v.y; w[2] = v.z; w[3] = v.w;
        }
        __syncthreads();
#pragma unroll 4
        for (int k = 0; k < 64; ++k) {
            float a[8], b[8];
#pragma unroll
            for (int i = 0; i < 8; ++i) a[i] = At[(r0 + i) * AT_S + k];
            *(float4*)&b[0] = *(float4*)&Wl[k * F + c0];
            *(float4*)&b[4] = *(float4*)&Wl[k * F + c0 + 4];
#pragma unroll
            for (int i = 0; i < 8; ++i)
#pragma unroll
                for (int j = 0; j < 8; ++j)
                    acc[i][j] = fmaf(a[i], b[j], acc[i][j]);
        }
    }

    float bv[8];
    *(float4*)&bv[0] = *(const float4*)(bias + c0);
    *(float4*)&bv[4] = *(const float4*)(bias + c0 + 4);

    float s[8], q[8];
#pragma unroll
    for (int j = 0; j < 8; ++j) { s[j] = 0.f; q[j] = 0.f; }

#pragma unroll
    for (int i = 0; i < 8; ++i) {
        int gr = row0 + r0 + i;
        if (gr < N) {
            float vv[8];
#pragma unroll
            for (int j = 0; j < 8; ++j) {
                float u = acc[i][j] + bv[j];
                u = u > 0.f ? u : 0.f;
                vv[j] = u; s[j] += u; q[j] += u * u;
            }
            *(float4*)(C + (size_t)gr * F + c0)     = *(float4*)&vv[0];
            *(float4*)(C + (size_t)gr * F + c0 + 4) = *(float4*)&vv[4];
        }
    }

    if (stats) {
        __syncthreads();
        float* cs = At;
        float* cq = At + F;
        if (t < F) { cs[t] = 0.f; cq[t] = 0.f; }
        __syncthreads();
#pragma unroll
        for (int j = 0; j < 8; ++j) {
            atomicAdd(&cs[c0 + j], s[j]);
            atomicAdd(&cq[c0 + j], q[j]);
        }
        __syncthreads();
        if (t < F) {
            atomicAdd(&stats[t],     cs[t]);
            atomicAdd(&stats[F + t], cq[t]);
        }
    }
}

__global__ void k_bn_coef(const float* __restrict__ stats,
                          const float* __restrict__ gamma,
                          const float* __restrict__ beta,
                          float invN, float* __restrict__ coef)
{
    int f = threadIdx.x;
    float mean = stats[f] * invN;
    float var  = stats[F + f] * invN - mean * mean;
    float a = gamma[f] * rsqrtf(var + BN_EPS);
    coef[f]     = a;
    coef[F + f] = beta[f] - mean * a;
}

__global__ __launch_bounds__(256) void k_bn_pool(
    float* zh, const float* __restrict__ coef,
    const int* __restrict__ batch, float* outL, int N)
{
    int idx = blockIdx.x * 256 + threadIdx.x;
    int n = idx >> 5;
    if (n >= N) return;
    int f = (idx & 31) << 2;
    float4 v = *(const float4*)(zh + (size_t)n * F + f);
    float4 a = *(const float4*)(coef + f);
    float4 c = *(const float4*)(coef + F + f);
    float4 y;
    y.x = fmaf(v.x, a.x, c.x);
    y.y = fmaf(v.y, a.y, c.y);
    y.z = fmaf(v.z, a.z, c.z);
    y.w = fmaf(v.w, a.w, c.w);
    *(float4*)(zh + (size_t)n * F + f) = y;
    int g = batch[n];
    float* p = outL + (size_t)g * 384 + f;
    atomicAdd(p + 0, y.x);
    atomicAdd(p + 1, y.y);
    atomicAdd(p + 2, y.z);
    atomicAdd(p + 3, y.w);
}

extern "C" void kernel_launch(void* const* d_in, const int* in_sizes, int n_in,
                              void* d_out, int out_size, void* d_ws, size_t ws_size,
                              hipStream_t stream)
{
    const float* x     = (const float*)d_in[0];
    const int*   ei    = (const int*)  d_in[1];
    const int*   batch = (const int*)  d_in[2];
    const float* W1    = (const float*)d_in[3];
    const float* b1    = (const float*)d_in[4];
    const float* W2    = (const float*)d_in[5];
    const float* b2    = (const float*)d_in[6];
    const float* gamma = (const float*)d_in[7];
    const float* beta  = (const float*)d_in[8];

    const int N = in_sizes[0] / F;      // 100000
    const int E = in_sizes[1] / 2;      // 1600000
    const int* src = ei;
    const int* dst = ei + E;
    float* out = (float*)d_out;

    const size_t NF = (size_t)N * F;
    float* B0    = (float*)d_ws;            // NF
    float* B1    = B0 + NF;                 // NF
    float* stats = B1 + NF;                 // 768
    float* coef  = stats + 768;             // 768
    int*   deg    = (int*)(coef + 768);     // N
    int*   rowptr = deg + N;                // N+1
    int*   cursor = rowptr + N + 1;         // N
    int*   bsum   = cursor + N;             // 256
    int*   esrc   = bsum + 256;             // E

    hipMemsetAsync(out, 0, (size_t)out_size * sizeof(float), stream);
    hipMemsetAsync(stats, 0, 768 * sizeof(float), stream);
    hipMemsetAsync(deg, 0, (size_t)N * sizeof(int), stream);

    // ---- CSR build (once; reused by all 3 layers) ----
    const int nblk = (N + 1023) / 1024;     // 98 <= 256
    k_hist <<<(E + 255) / 256, 256, 0, stream>>>(dst, deg, E);
    k_scan1<<<nblk, 256, 0, stream>>>(deg, rowptr, bsum, N);
    k_scan2<<<1, 256, 0, stream>>>(bsum, nblk);
    k_scan3<<<nblk, 256, 0, stream>>>(rowptr, cursor, bsum, N, E);
    k_fill <<<(E + 255) / 256, 256, 0, stream>>>(src, dst, cursor, esrc, E);

    const float invN = 1.0f / (float)N;
    const int gemm_grid = (N + 127) / 128;
    const int pool_grid = (int)((NF / 4 + 255) / 256);
    const int agg_grid  = (int)(((size_t)N * 64 + 255) / 256);

    for (int L = 0; L < 3; ++L) {
        const float* h  = (L == 0) ? x : ((L == 1) ? B0 : B1);
        float* z0 = (L == 1) ? B1 : B0;
        float* tb = (L == 1) ? B0 : B1;

        k_agg<<<agg_grid, 256, 0, stream>>>(h, rowptr, esrc, z0, N);               // z0 = h + agg
        k_gemm<<<gemm_grid, 256, 0, stream>>>(z0, W1 + (size_t)L * F * F, b1 + L * F,
                                              tb, N, nullptr);                      // t = relu(z0@W1+b1)
        k_gemm<<<gemm_grid, 256, 0, stream>>>(tb, W2 + (size_t)L * F * F, b2 + L * F,
                                              z0, N, stats + L * 256);              // z = relu(t@W2+b2) + stats
        k_bn_coef<<<1, F, 0, stream>>>(stats + L * 256, gamma + L * F, beta + L * F,
                                       invN, coef + L * 256);
        k_bn_pool<<<pool_grid, 256, 0, stream>>>(z0, coef + L * 256, batch,
                                                 out + L * F, N);                   // BN + pool
    }
}

// Round 3
// 1133.256 us; speedup vs baseline: 8.3720x; 1.7051x over previous
//
#include <hip/hip_runtime.h>

#define F 128
#define BN_EPS 1e-5f
#define NG 512    // NUM_GRAPHS
#define AT_S 65   // A-tile LDS stride: 64 k + 1 pad -> conflict-free scalar reads

// ================= CSR build (counting sort of edges by dst) =================

__global__ __launch_bounds__(256) void k_hist(const int* __restrict__ dst,
                                              int* __restrict__ deg, int E)
{
    int e = blockIdx.x * 256 + threadIdx.x;
    if (e < E) atomicAdd(&deg[dst[e]], 1);
}

__global__ __launch_bounds__(256) void k_scan1(const int* __restrict__ deg,
                                               int* __restrict__ rowptr,
                                               int* __restrict__ bsum, int N)
{
    __shared__ int lds[256];
    const int t = threadIdx.x;
    const int base = blockIdx.x * 1024 + t * 4;
    int4 v = make_int4(0, 0, 0, 0);
    if (base + 3 < N) v = *(const int4*)(deg + base);
    else {
        int* vv = (int*)&v;
        for (int i = 0; i < 4; ++i) vv[i] = (base + i < N) ? deg[base + i] : 0;
    }
    int s = v.x + v.y + v.z + v.w;
    lds[t] = s;
    __syncthreads();
    for (int off = 1; off < 256; off <<= 1) {
        int u = (t >= off) ? lds[t - off] : 0;
        __syncthreads();
        if (t >= off) lds[t] += u;
        __syncthreads();
    }
    int excl = lds[t] - s;
    if (t == 255) bsum[blockIdx.x] = lds[255];
    int4 o;
    o.x = excl; o.y = o.x + v.x; o.z = o.y + v.y; o.w = o.z + v.z;
    if (base + 3 < N) *(int4*)(rowptr + base) = o;
    else {
        int* oo = (int*)&o;
        for (int i = 0; i < 4; ++i) if (base + i < N) rowptr[base + i] = oo[i];
    }
}

__global__ __launch_bounds__(256) void k_scan2(int* __restrict__ bsum, int nblk)
{
    __shared__ int lds[256];
    const int t = threadIdx.x;
    int s = (t < nblk) ? bsum[t] : 0;
    lds[t] = s;
    __syncthreads();
    for (int off = 1; off < 256; off <<= 1) {
        int u = (t >= off) ? lds[t - off] : 0;
        __syncthreads();
        if (t >= off) lds[t] += u;
        __syncthreads();
    }
    if (t < nblk) bsum[t] = lds[t] - s;
}

__global__ __launch_bounds__(256) void k_scan3(int* __restrict__ rowptr,
                                               int* __restrict__ cursor,
                                               const int* __restrict__ bsum,
                                               int N, int E)
{
    int i = blockIdx.x * 1024 + threadIdx.x * 4;
    int off = bsum[blockIdx.x];
    for (int k = 0; k < 4; ++k) {
        int idx = i + k;
        if (idx < N) {
            int v = rowptr[idx] + off;
            rowptr[idx] = v;
            cursor[idx] = v;
        }
    }
    if (blockIdx.x == 0 && threadIdx.x == 0) rowptr[N] = E;
}

__global__ __launch_bounds__(256) void k_fill(const int* __restrict__ src,
                                              const int* __restrict__ dst,
                                              int* __restrict__ cursor,
                                              int* __restrict__ esrc, int E)
{
    int e = blockIdx.x * 256 + threadIdx.x;
    if (e < E) {
        int pos = atomicAdd(&cursor[dst[e]], 1);
        esrc[pos] = src[e];
    }
}

// graph segment pointers: batch is sorted; gptr[g] = lower_bound(batch, g)
__global__ __launch_bounds__(256) void k_gptr(const int* __restrict__ batch,
                                              int* __restrict__ gptr, int N)
{
    int g = blockIdx.x * 256 + threadIdx.x;
    if (g > NG) return;
    int lo = 0, hi = N;
    while (lo < hi) {
        int mid = (lo + hi) >> 1;
        if (batch[mid] < g) lo = mid + 1; else hi = mid;
    }
    gptr[g] = lo;
}

// ============ aggregate: z0[n] = h[n] + sum_{j in adj(n)} h[src_j] ============
__global__ __launch_bounds__(256) void k_agg(const float* __restrict__ h,
                                             const int* __restrict__ rowptr,
                                             const int* __restrict__ esrc,
                                             float* __restrict__ z0, int N)
{
    int n = (blockIdx.x * 256 + threadIdx.x) >> 6;
    if (n >= N) return;
    n = __builtin_amdgcn_readfirstlane(n);        // wave-uniform -> scalar loads below
    const int lane = threadIdx.x & 63;
    const int beg = rowptr[n], end = rowptr[n + 1];
    const float2* h2 = (const float2*)h;

    float2 a0 = h2[(size_t)n * 64 + lane];
    float2 a1 = make_float2(0.f, 0.f);
    int j = beg;
    for (; j + 2 <= end; j += 2) {
        int s0 = esrc[j], s1 = esrc[j + 1];
        float2 v0 = h2[(size_t)s0 * 64 + lane];
        float2 v1 = h2[(size_t)s1 * 64 + lane];
        a0.x += v0.x; a0.y += v0.y;
        a1.x += v1.x; a1.y += v1.y;
    }
    if (j < end) {
        int s = esrc[j];
        float2 v = h2[(size_t)s * 64 + lane];
        a0.x += v.x; a0.y += v.y;
    }
    a0.x += a1.x; a0.y += a1.y;
    ((float2*)z0)[(size_t)n * 64 + lane] = a0;
}

// ---------------- GEMM: C = relu(A @ W + bias), optional BN-stats accumulation ----------------
__global__ __launch_bounds__(256, 2) void k_gemm(
    const float* __restrict__ A, const float* __restrict__ W,
    const float* __restrict__ bias, float* __restrict__ C,
    int N, float* stats)
{
    __shared__ float Wl[64 * F];
    __shared__ float At[F * AT_S];
    const int t = threadIdx.x;
    const int row0 = blockIdx.x << 7;
    const int tr = t >> 4, tc = t & 15;
    const int r0 = tr << 3, c0 = tc << 3;

    float acc[8][8];
#pragma unroll
    for (int i = 0; i < 8; ++i)
#pragma unroll
        for (int j = 0; j < 8; ++j) acc[i][j] = 0.f;

    for (int kb = 0; kb < 2; ++kb) {
        if (kb) __syncthreads();
        const float* Wsrc = W + (size_t)(kb << 6) * F;
#pragma unroll
        for (int i = 0; i < 8; ++i) {
            int idx = t + (i << 8);
            ((float4*)Wl)[idx] = ((const float4*)Wsrc)[idx];
        }
#pragma unroll
        for (int i = 0; i < 8; ++i) {
            int idx = t + (i << 8);
            int row = idx >> 4;
            int k4  = (idx & 15) << 2;
            float4 v = make_float4(0.f, 0.f, 0.f, 0.f);
            int gr = row0 + row;
            if (gr < N) v = *(const float4*)(A + (size_t)gr * F + (kb << 6) + k4);
            float* w = At + row * AT_S + k4;
            w[0] = v.x; w[1] = v.y; w[2] = v.z; w[3] = v.w;
        }
        __syncthreads();
#pragma unroll 4
        for (int k = 0; k < 64; ++k) {
            float a[8], b[8];
#pragma unroll
            for (int i = 0; i < 8; ++i) a[i] = At[(r0 + i) * AT_S + k];
            *(float4*)&b[0] = *(float4*)&Wl[k * F + c0];
            *(float4*)&b[4] = *(float4*)&Wl[k * F + c0 + 4];
#pragma unroll
            for (int i = 0; i < 8; ++i)
#pragma unroll
                for (int j = 0; j < 8; ++j)
                    acc[i][j] = fmaf(a[i], b[j], acc[i][j]);
        }
    }

    float bv[8];
    *(float4*)&bv[0] = *(const float4*)(bias + c0);
    *(float4*)&bv[4] = *(const float4*)(bias + c0 + 4);

    float s[8], q[8];
#pragma unroll
    for (int j = 0; j < 8; ++j) { s[j] = 0.f; q[j] = 0.f; }

#pragma unroll
    for (int i = 0; i < 8; ++i) {
        int gr = row0 + r0 + i;
        if (gr < N) {
            float vv[8];
#pragma unroll
            for (int j = 0; j < 8; ++j) {
                float u = acc[i][j] + bv[j];
                u = u > 0.f ? u : 0.f;
                vv[j] = u; s[j] += u; q[j] += u * u;
            }
            *(float4*)(C + (size_t)gr * F + c0)     = *(float4*)&vv[0];
            *(float4*)(C + (size_t)gr * F + c0 + 4) = *(float4*)&vv[4];
        }
    }

    if (stats) {
        __syncthreads();
        float* cs = At;
        float* cq = At + F;
        if (t < F) { cs[t] = 0.f; cq[t] = 0.f; }
        __syncthreads();
#pragma unroll
        for (int j = 0; j < 8; ++j) {
            atomicAdd(&cs[c0 + j], s[j]);
            atomicAdd(&cq[c0 + j], q[j]);
        }
        __syncthreads();
        if (t < F) {
            atomicAdd(&stats[t],     cs[t]);
            atomicAdd(&stats[F + t], cq[t]);
        }
    }
}

__global__ void k_bn_coef(const float* __restrict__ stats,
                          const float* __restrict__ gamma,
                          const float* __restrict__ beta,
                          float invN, float* __restrict__ coef)
{
    int f = threadIdx.x;
    float mean = stats[f] * invN;
    float var  = stats[F + f] * invN - mean * mean;
    float a = gamma[f] * rsqrtf(var + BN_EPS);
    coef[f]     = a;
    coef[F + f] = beta[f] - mean * a;
}

// ---- BN apply (in-place) + segmented global_add_pool: one block per graph, NO atomics ----
__global__ __launch_bounds__(256) void k_bn_pool2(
    float* __restrict__ zh, const float* __restrict__ coef,
    const int* __restrict__ gptr, float* __restrict__ outL)
{
    const int g = blockIdx.x;
    const int beg = gptr[g], end = gptr[g + 1];
    const int t = threadIdx.x;
    const int wave = t >> 6, lane = t & 63;

    float2 a = ((const float2*)coef)[lane];
    float2 c = ((const float2*)(coef + F))[lane];
    float2 acc = make_float2(0.f, 0.f);
    float2* z2 = (float2*)zh;

    for (int n = beg + wave; n < end; n += 4) {
        float2 v = z2[(size_t)n * 64 + lane];
        v.x = fmaf(v.x, a.x, c.x);
        v.y = fmaf(v.y, a.y, c.y);
        z2[(size_t)n * 64 + lane] = v;      // becomes h for next layer
        acc.x += v.x; acc.y += v.y;
    }

    __shared__ float2 red[4][64];
    red[wave][lane] = acc;
    __syncthreads();
    if (wave == 0) {
        float2 r = red[0][lane];
        r.x += red[1][lane].x + red[2][lane].x + red[3][lane].x;
        r.y += red[1][lane].y + red[2][lane].y + red[3][lane].y;
        ((float2*)outL)[(size_t)g * 192 + lane] = r;   // out row stride 384 floats
    }
}

extern "C" void kernel_launch(void* const* d_in, const int* in_sizes, int n_in,
                              void* d_out, int out_size, void* d_ws, size_t ws_size,
                              hipStream_t stream)
{
    const float* x     = (const float*)d_in[0];
    const int*   ei    = (const int*)  d_in[1];
    const int*   batch = (const int*)  d_in[2];
    const float* W1    = (const float*)d_in[3];
    const float* b1    = (const float*)d_in[4];
    const float* W2    = (const float*)d_in[5];
    const float* b2    = (const float*)d_in[6];
    const float* gamma = (const float*)d_in[7];
    const float* beta  = (const float*)d_in[8];

    const int N = in_sizes[0] / F;      // 100000
    const int E = in_sizes[1] / 2;      // 1600000
    const int* src = ei;
    const int* dst = ei + E;
    float* out = (float*)d_out;

    const size_t NF = (size_t)N * F;
    float* B0    = (float*)d_ws;            // NF
    float* B1    = B0 + NF;                 // NF
    float* stats = B1 + NF;                 // 768
    float* coef  = stats + 768;             // 768
    int*   deg    = (int*)(coef + 768);     // N
    int*   rowptr = deg + N;                // N+1
    int*   cursor = rowptr + N + 1;         // N
    int*   bsum   = cursor + N;             // 256
    int*   gptr   = bsum + 256;             // NG+1
    int*   esrc   = gptr + NG + 1;          // E

    hipMemsetAsync(stats, 0, 768 * sizeof(float), stream);
    hipMemsetAsync(deg, 0, (size_t)N * sizeof(int), stream);

    // ---- CSR build + graph segments (once; reused by all 3 layers) ----
    const int nblk = (N + 1023) / 1024;
    k_hist <<<(E + 255) / 256, 256, 0, stream>>>(dst, deg, E);
    k_scan1<<<nblk, 256, 0, stream>>>(deg, rowptr, bsum, N);
    k_scan2<<<1, 256, 0, stream>>>(bsum, nblk);
    k_scan3<<<nblk, 256, 0, stream>>>(rowptr, cursor, bsum, N, E);
    k_fill <<<(E + 255) / 256, 256, 0, stream>>>(src, dst, cursor, esrc, E);
    k_gptr <<<(NG + 256) / 256, 256, 0, stream>>>(batch, gptr, N);

    const float invN = 1.0f / (float)N;
    const int gemm_grid = (N + 127) / 128;
    const int agg_grid  = (int)(((size_t)N * 64 + 255) / 256);

    for (int L = 0; L < 3; ++L) {
        const float* h  = (L == 0) ? x : ((L == 1) ? B0 : B1);
        float* z0 = (L == 1) ? B1 : B0;
        float* tb = (L == 1) ? B0 : B1;

        k_agg<<<agg_grid, 256, 0, stream>>>(h, rowptr, esrc, z0, N);               // z0 = h + agg
        k_gemm<<<gemm_grid, 256, 0, stream>>>(z0, W1 + (size_t)L * F * F, b1 + L * F,
                                              tb, N, nullptr);                      // t = relu(z0@W1+b1)
        k_gemm<<<gemm_grid, 256, 0, stream>>>(tb, W2 + (size_t)L * F * F, b2 + L * F,
                                              z0, N, stats + L * 256);              // z = relu(t@W2+b2) + stats
        k_bn_coef<<<1, F, 0, stream>>>(stats + L * 256, gamma + L * F, beta + L * F,
                                       invN, coef + L * 256);
        k_bn_pool2<<<NG, 256, 0, stream>>>(z0, coef + L * 256, gptr, out + L * F);  // BN + pool
    }
}

// Round 5
// 941.169 us; speedup vs baseline: 10.0807x; 1.2041x over previous
//
#include <hip/hip_runtime.h>

#define F 128
#define BN_EPS 1e-5f
#define NG 512    // NUM_GRAPHS
#define WT_S 72   // f16 LDS row stride (64 k + 8 pad) -> b128 reads 2-way/free

typedef __attribute__((ext_vector_type(8))) _Float16 half8;
typedef __attribute__((ext_vector_type(4))) _Float16 half4v;
typedef __attribute__((ext_vector_type(4))) float f32x4;

// ================= CSR build (counting sort of edges by dst) =================

__global__ __launch_bounds__(256) void k_hist(const int* __restrict__ dst,
                                              int* __restrict__ deg, int E)
{
    int e = blockIdx.x * 256 + threadIdx.x;
    if (e < E) atomicAdd(&deg[dst[e]], 1);
}

__global__ __launch_bounds__(256) void k_scan1(const int* __restrict__ deg,
                                               int* __restrict__ rowptr,
                                               int* __restrict__ bsum, int N)
{
    __shared__ int lds[256];
    const int t = threadIdx.x;
    const int base = blockIdx.x * 1024 + t * 4;
    int4 v = make_int4(0, 0, 0, 0);
    if (base + 3 < N) v = *(const int4*)(deg + base);
    else {
        int* vv = (int*)&v;
        for (int i = 0; i < 4; ++i) vv[i] = (base + i < N) ? deg[base + i] : 0;
    }
    int s = v.x + v.y + v.z + v.w;
    lds[t] = s;
    __syncthreads();
    for (int off = 1; off < 256; off <<= 1) {
        int u = (t >= off) ? lds[t - off] : 0;
        __syncthreads();
        if (t >= off) lds[t] += u;
        __syncthreads();
    }
    int excl = lds[t] - s;
    if (t == 255) bsum[blockIdx.x] = lds[255];
    int4 o;
    o.x = excl; o.y = o.x + v.x; o.z = o.y + v.y; o.w = o.z + v.z;
    if (base + 3 < N) *(int4*)(rowptr + base) = o;
    else {
        int* oo = (int*)&o;
        for (int i = 0; i < 4; ++i) if (base + i < N) rowptr[base + i] = oo[i];
    }
}

__global__ __launch_bounds__(256) void k_scan2(int* __restrict__ bsum, int nblk)
{
    __shared__ int lds[256];
    const int t = threadIdx.x;
    int s = (t < nblk) ? bsum[t] : 0;
    lds[t] = s;
    __syncthreads();
    for (int off = 1; off < 256; off <<= 1) {
        int u = (t >= off) ? lds[t - off] : 0;
        __syncthreads();
        if (t >= off) lds[t] += u;
        __syncthreads();
    }
    if (t < nblk) bsum[t] = lds[t] - s;
}

__global__ __launch_bounds__(256) void k_scan3(int* __restrict__ rowptr,
                                               int* __restrict__ cursor,
                                               const int* __restrict__ bsum,
                                               int N, int E)
{
    int i = blockIdx.x * 1024 + threadIdx.x * 4;
    int off = bsum[blockIdx.x];
    for (int k = 0; k < 4; ++k) {
        int idx = i + k;
        if (idx < N) {
            int v = rowptr[idx] + off;
            rowptr[idx] = v;
            cursor[idx] = v;
        }
    }
    if (blockIdx.x == 0 && threadIdx.x == 0) rowptr[N] = E;
}

__global__ __launch_bounds__(256) void k_fill(const int* __restrict__ src,
                                              const int* __restrict__ dst,
                                              int* __restrict__ cursor,
                                              int* __restrict__ esrc, int E)
{
    int e = blockIdx.x * 256 + threadIdx.x;
    if (e < E) {
        int pos = atomicAdd(&cursor[dst[e]], 1);
        esrc[pos] = src[e];
    }
}

__global__ __launch_bounds__(256) void k_gptr(const int* __restrict__ batch,
                                              int* __restrict__ gptr, int N)
{
    int g = blockIdx.x * 256 + threadIdx.x;
    if (g > NG) return;
    int lo = 0, hi = N;
    while (lo < hi) {
        int mid = (lo + hi) >> 1;
        if (batch[mid] < g) lo = mid + 1; else hi = mid;
    }
    gptr[g] = lo;
}

// ============ aggregate: z0[n] = h[n] + sum_{j in adj(n)} h[src_j] ============
__global__ __launch_bounds__(256) void k_agg(const float* __restrict__ h,
                                             const int* __restrict__ rowptr,
                                             const int* __restrict__ esrc,
                                             float* __restrict__ z0, int N)
{
    int n = (blockIdx.x * 256 + threadIdx.x) >> 6;
    if (n >= N) return;
    n = __builtin_amdgcn_readfirstlane(n);        // wave-uniform -> scalar loads
    const int lane = threadIdx.x & 63;
    const int beg = rowptr[n], end = rowptr[n + 1];
    const float2* h2 = (const float2*)h;

    float2 a0 = h2[(size_t)n * 64 + lane];
    float2 a1 = make_float2(0.f, 0.f);
    int j = beg;
    for (; j + 2 <= end; j += 2) {
        int s0 = esrc[j], s1 = esrc[j + 1];
        float2 v0 = h2[(size_t)s0 * 64 + lane];
        float2 v1 = h2[(size_t)s1 * 64 + lane];
        a0.x += v0.x; a0.y += v0.y;
        a1.x += v1.x; a1.y += v1.y;
    }
    if (j < end) {
        int s = esrc[j];
        float2 v = h2[(size_t)s * 64 + lane];
        a0.x += v.x; a0.y += v.y;
    }
    a0.x += a1.x; a0.y += a1.y;
    ((float2*)z0)[(size_t)n * 64 + lane] = a0;
}

// ======== MFMA GEMM: C = relu(A @ W + bias) in fp16xfp16->fp32, 128x128 tile ========
// 4 waves in 2x2 grid, each wave 64x64 (4x4 tiles of 16x16x32).
// A staged [row][k] fp16, W staged transposed [col][k] fp16; stride 72 halves.
__global__ __launch_bounds__(256, 3) void k_gemm_mfma(
    const float* __restrict__ A, const float* __restrict__ W,
    const float* __restrict__ bias, float* __restrict__ C,
    int N, float* stats)
{
    __shared__ _Float16 Al[128 * WT_S];
    __shared__ _Float16 Wl[128 * WT_S];
    const int t = threadIdx.x;
    const int row0 = blockIdx.x << 7;
    const int wave = t >> 6, lane = t & 63;
    const int wr = wave >> 1, wc = wave & 1;
    const int lrow = lane & 15, quad = lane >> 4;

    f32x4 acc[4][4];
#pragma unroll
    for (int i = 0; i < 4; ++i)
#pragma unroll
        for (int j = 0; j < 4; ++j) acc[i][j] = (f32x4){0.f, 0.f, 0.f, 0.f};

    for (int kb = 0; kb < 2; ++kb) {
        if (kb) __syncthreads();
        // ---- stage A rows [row0..row0+128), k in [kb*64, kb*64+64), fp32 -> fp16
#pragma unroll
        for (int i = 0; i < 8; ++i) {
            int idx = t + (i << 8);             // 0..2047, one float4 (4 k) each
            int row = idx >> 4;
            int k4  = (idx & 15) << 2;
            float4 v = make_float4(0.f, 0.f, 0.f, 0.f);
            int gr = row0 + row;
            if (gr < N) v = *(const float4*)(A + (size_t)gr * F + (kb << 6) + k4);
            half4v s;
            s.x = (_Float16)v.x; s.y = (_Float16)v.y;
            s.z = (_Float16)v.z; s.w = (_Float16)v.w;
            *(half4v*)(Al + row * WT_S + k4) = s;
        }
        // ---- stage W^T: Wl[col][k] <- W[kb*64+k][col], fp32 -> fp16
        {
            int col = t & 127, ks = (t >> 7) << 5;   // ks = 0 or 32
            const float* wp = W + (size_t)((kb << 6) + ks) * F + col;
#pragma unroll
            for (int i = 0; i < 4; ++i) {
                half8 s;
#pragma unroll
                for (int j = 0; j < 8; ++j) s[j] = (_Float16)wp[(size_t)(i * 8 + j) * F];
                *(half8*)(Wl + col * WT_S + ks + (i << 3)) = s;
            }
        }
        __syncthreads();
        // ---- compute: 2 k-chunks of 32 per kb
#pragma unroll
        for (int kc = 0; kc < 2; ++kc) {
            half8 af[4], bfr[4];
#pragma unroll
            for (int i = 0; i < 4; ++i)
                af[i] = *(half8*)(Al + (wr * 64 + i * 16 + lrow) * WT_S + kc * 32 + quad * 8);
#pragma unroll
            for (int j = 0; j < 4; ++j)
                bfr[j] = *(half8*)(Wl + (wc * 64 + j * 16 + lrow) * WT_S + kc * 32 + quad * 8);
#pragma unroll
            for (int i = 0; i < 4; ++i)
#pragma unroll
                for (int j = 0; j < 4; ++j)
                    acc[i][j] = __builtin_amdgcn_mfma_f32_16x16x32_f16(
                        af[i], bfr[j], acc[i][j], 0, 0, 0);
        }
    }

    // ---- epilogue: bias + relu + store + (optional) BN-stats
    const int colbase = wc * 64 + lrow;
    float bv[4];
#pragma unroll
    for (int j = 0; j < 4; ++j) bv[j] = bias[colbase + j * 16];

    float s[4], q[4];
#pragma unroll
    for (int j = 0; j < 4; ++j) { s[j] = 0.f; q[j] = 0.f; }

#pragma unroll
    for (int i = 0; i < 4; ++i) {
#pragma unroll
        for (int r = 0; r < 4; ++r) {
            int gr = row0 + wr * 64 + i * 16 + quad * 4 + r;
            if (gr < N) {
#pragma unroll
                for (int j = 0; j < 4; ++j) {
                    float u = acc[i][j][r] + bv[j];
                    u = fmaxf(u, 0.f);
                    C[(size_t)gr * F + colbase + j * 16] = u;
                    s[j] += u; q[j] += u * u;
                }
            }
        }
    }

    if (stats) {
        __syncthreads();                 // all frag reads done; reuse Al
        float* cs = (float*)Al;
        float* cq = cs + F;
        if (t < F) { cs[t] = 0.f; cq[t] = 0.f; }
        __syncthreads();
#pragma unroll
        for (int j = 0; j < 4; ++j) {
            atomicAdd(&cs[colbase + j * 16], s[j]);
            atomicAdd(&cq[colbase + j * 16], q[j]);
        }
        __syncthreads();
        if (t < F) {
            atomicAdd(&stats[t],     cs[t]);
            atomicAdd(&stats[F + t], cq[t]);
        }
    }
}

__global__ void k_bn_coef(const float* __restrict__ stats,
                          const float* __restrict__ gamma,
                          const float* __restrict__ beta,
                          float invN, float* __restrict__ coef)
{
    int f = threadIdx.x;
    float mean = stats[f] * invN;
    float var  = stats[F + f] * invN - mean * mean;
    float a = gamma[f] * rsqrtf(var + BN_EPS);
    coef[f]     = a;
    coef[F + f] = beta[f] - mean * a;
}

// ---- BN apply (in-place) + segmented global_add_pool: one block per graph ----
__global__ __launch_bounds__(256) void k_bn_pool2(
    float* __restrict__ zh, const float* __restrict__ coef,
    const int* __restrict__ gptr, float* __restrict__ outL)
{
    const int g = blockIdx.x;
    const int beg = gptr[g], end = gptr[g + 1];
    const int t = threadIdx.x;
    const int wave = t >> 6, lane = t & 63;

    float2 a = ((const float2*)coef)[lane];
    float2 c = ((const float2*)(coef + F))[lane];
    float2 acc = make_float2(0.f, 0.f);
    float2* z2 = (float2*)zh;

    for (int n = beg + wave; n < end; n += 4) {
        float2 v = z2[(size_t)n * 64 + lane];
        v.x = fmaf(v.x, a.x, c.x);
        v.y = fmaf(v.y, a.y, c.y);
        z2[(size_t)n * 64 + lane] = v;      // becomes h for next layer
        acc.x += v.x; acc.y += v.y;
    }

    __shared__ float2 red[4][64];
    red[wave][lane] = acc;
    __syncthreads();
    if (wave == 0) {
        float2 r = red[0][lane];
        r.x += red[1][lane].x + red[2][lane].x + red[3][lane].x;
        r.y += red[1][lane].y + red[2][lane].y + red[3][lane].y;
        ((float2*)outL)[(size_t)g * 192 + lane] = r;   // out row stride 384 floats
    }
}

extern "C" void kernel_launch(void* const* d_in, const int* in_sizes, int n_in,
                              void* d_out, int out_size, void* d_ws, size_t ws_size,
                              hipStream_t stream)
{
    const float* x     = (const float*)d_in[0];
    const int*   ei    = (const int*)  d_in[1];
    const int*   batch = (const int*)  d_in[2];
    const float* W1    = (const float*)d_in[3];
    const float* b1    = (const float*)d_in[4];
    const float* W2    = (const float*)d_in[5];
    const float* b2    = (const float*)d_in[6];
    const float* gamma = (const float*)d_in[7];
    const float* beta  = (const float*)d_in[8];

    const int N = in_sizes[0] / F;      // 100000
    const int E = in_sizes[1] / 2;      // 1600000
    const int* src = ei;
    const int* dst = ei + E;
    float* out = (float*)d_out;

    const size_t NF = (size_t)N * F;
    float* B0    = (float*)d_ws;            // NF
    float* B1    = B0 + NF;                 // NF
    float* stats = B1 + NF;                 // 768
    float* coef  = stats + 768;             // 768
    int*   deg    = (int*)(coef + 768);     // N
    int*   rowptr = deg + N;                // N+1
    int*   cursor = rowptr + N + 1;         // N
    int*   bsum   = cursor + N;             // 256
    int*   gptr   = bsum + 256;             // NG+1
    int*   esrc   = gptr + NG + 1;          // E

    hipMemsetAsync(stats, 0, 768 * sizeof(float), stream);
    hipMemsetAsync(deg, 0, (size_t)N * sizeof(int), stream);

    // ---- CSR build + graph segments (once; reused by all 3 layers) ----
    const int nblk = (N + 1023) / 1024;
    k_hist <<<(E + 255) / 256, 256, 0, stream>>>(dst, deg, E);
    k_scan1<<<nblk, 256, 0, stream>>>(deg, rowptr, bsum, N);
    k_scan2<<<1, 256, 0, stream>>>(bsum, nblk);
    k_scan3<<<nblk, 256, 0, stream>>>(rowptr, cursor, bsum, N, E);
    k_fill <<<(E + 255) / 256, 256, 0, stream>>>(src, dst, cursor, esrc, E);
    k_gptr <<<(NG + 256) / 256, 256, 0, stream>>>(batch, gptr, N);

    const float invN = 1.0f / (float)N;
    const int gemm_grid = (N + 127) / 128;
    const int agg_grid  = (int)(((size_t)N * 64 + 255) / 256);

    for (int L = 0; L < 3; ++L) {
        const float* h  = (L == 0) ? x : ((L == 1) ? B0 : B1);
        float* z0 = (L == 1) ? B1 : B0;
        float* tb = (L == 1) ? B0 : B1;

        k_agg<<<agg_grid, 256, 0, stream>>>(h, rowptr, esrc, z0, N);
        k_gemm_mfma<<<gemm_grid, 256, 0, stream>>>(z0, W1 + (size_t)L * F * F,
                                                   b1 + L * F, tb, N, nullptr);
        k_gemm_mfma<<<gemm_grid, 256, 0, stream>>>(tb, W2 + (size_t)L * F * F,
                                                   b2 + L * F, z0, N, stats + L * 256);
        k_bn_coef<<<1, F, 0, stream>>>(stats + L * 256, gamma + L * F, beta + L * F,
                                       invN, coef + L * 256);
        k_bn_pool2<<<NG, 256, 0, stream>>>(z0, coef + L * 256, gptr, out + L * F);
    }
}

// Round 6
// 743.366 us; speedup vs baseline: 12.7630x; 1.2661x over previous
//
#include <hip/hip_runtime.h>

#define F 128
#define BN_EPS 1e-5f
#define NG 512    // NUM_GRAPHS
#define WT_S 72   // f16 LDS row stride (64 k + 8 pad) -> b128 reads 2-way/free

typedef __attribute__((ext_vector_type(8))) _Float16 half8;
typedef __attribute__((ext_vector_type(2))) _Float16 half2v;
typedef __attribute__((ext_vector_type(4))) float f32x4;

// ================= CSR build (counting sort of edges by dst) =================

__global__ __launch_bounds__(256) void k_hist(const int* __restrict__ dst,
                                              int* __restrict__ deg, int E)
{
    int e = blockIdx.x * 256 + threadIdx.x;
    if (e < E) atomicAdd(&deg[dst[e]], 1);
}

__global__ __launch_bounds__(256) void k_scan1(const int* __restrict__ deg,
                                               int* __restrict__ rowptr,
                                               int* __restrict__ bsum, int N)
{
    __shared__ int lds[256];
    const int t = threadIdx.x;
    const int base = blockIdx.x * 1024 + t * 4;
    int4 v = make_int4(0, 0, 0, 0);
    if (base + 3 < N) v = *(const int4*)(deg + base);
    else {
        int* vv = (int*)&v;
        for (int i = 0; i < 4; ++i) vv[i] = (base + i < N) ? deg[base + i] : 0;
    }
    int s = v.x + v.y + v.z + v.w;
    lds[t] = s;
    __syncthreads();
    for (int off = 1; off < 256; off <<= 1) {
        int u = (t >= off) ? lds[t - off] : 0;
        __syncthreads();
        if (t >= off) lds[t] += u;
        __syncthreads();
    }
    int excl = lds[t] - s;
    if (t == 255) bsum[blockIdx.x] = lds[255];
    int4 o;
    o.x = excl; o.y = o.x + v.x; o.z = o.y + v.y; o.w = o.z + v.z;
    if (base + 3 < N) *(int4*)(rowptr + base) = o;
    else {
        int* oo = (int*)&o;
        for (int i = 0; i < 4; ++i) if (base + i < N) rowptr[base + i] = oo[i];
    }
}

__global__ __launch_bounds__(256) void k_scan2(int* __restrict__ bsum, int nblk)
{
    __shared__ int lds[256];
    const int t = threadIdx.x;
    int s = (t < nblk) ? bsum[t] : 0;
    lds[t] = s;
    __syncthreads();
    for (int off = 1; off < 256; off <<= 1) {
        int u = (t >= off) ? lds[t - off] : 0;
        __syncthreads();
        if (t >= off) lds[t] += u;
        __syncthreads();
    }
    if (t < nblk) bsum[t] = lds[t] - s;
}

__global__ __launch_bounds__(256) void k_scan3(int* __restrict__ rowptr,
                                               int* __restrict__ cursor,
                                               const int* __restrict__ bsum,
                                               int N, int E)
{
    int i = blockIdx.x * 1024 + threadIdx.x * 4;
    int off = bsum[blockIdx.x];
    for (int k = 0; k < 4; ++k) {
        int idx = i + k;
        if (idx < N) {
            int v = rowptr[idx] + off;
            rowptr[idx] = v;
            cursor[idx] = v;
        }
    }
    if (blockIdx.x == 0 && threadIdx.x == 0) rowptr[N] = E;
}

__global__ __launch_bounds__(256) void k_fill(const int* __restrict__ src,
                                              const int* __restrict__ dst,
                                              int* __restrict__ cursor,
                                              int* __restrict__ esrc, int E)
{
    int e = blockIdx.x * 256 + threadIdx.x;
    if (e < E) {
        int pos = atomicAdd(&cursor[dst[e]], 1);
        esrc[pos] = src[e];
    }
}

__global__ __launch_bounds__(256) void k_gptr(const int* __restrict__ batch,
                                              int* __restrict__ gptr, int N)
{
    int g = blockIdx.x * 256 + threadIdx.x;
    if (g > NG) return;
    int lo = 0, hi = N;
    while (lo < hi) {
        int mid = (lo + hi) >> 1;
        if (batch[mid] < g) lo = mid + 1; else hi = mid;
    }
    gptr[g] = lo;
}

// ================= one-time fp16 conversions =================

// x (fp32 [N][128]) -> hh (fp16 [N][128])
__global__ __launch_bounds__(256) void k_x2h(const float* __restrict__ x,
                                             _Float16* __restrict__ hh, long n8)
{
    long i = (long)blockIdx.x * 256 + threadIdx.x;   // one half8 per thread
    if (i >= n8) return;
    float4 a = *(const float4*)(x + i * 8);
    float4 b = *(const float4*)(x + i * 8 + 4);
    half8 o;
    o[0] = (_Float16)a.x; o[1] = (_Float16)a.y; o[2] = (_Float16)a.z; o[3] = (_Float16)a.w;
    o[4] = (_Float16)b.x; o[5] = (_Float16)b.y; o[6] = (_Float16)b.z; o[7] = (_Float16)b.w;
    *(half8*)(hh + i * 8) = o;
}

// W1,W2 (fp32 [3][128][128] row-major [k][col]) -> Wt (fp16 [6][128][128] = [col][k])
// block b: matrix m=b>>3, colgroup cg=b&7 (16 cols each)
__global__ __launch_bounds__(256) void k_wconv(const float* __restrict__ W1,
                                               const float* __restrict__ W2,
                                               _Float16* __restrict__ Wt)
{
    int m = blockIdx.x >> 3, cg = blockIdx.x & 7;
    const float* Wsrc = (m < 3) ? (W1 + (size_t)m * F * F) : (W2 + (size_t)(m - 3) * F * F);
    int col = cg * 16 + (threadIdx.x >> 4);
    int k8  = (threadIdx.x & 15) * 8;
    half8 o;
#pragma unroll
    for (int j = 0; j < 8; ++j) o[j] = (_Float16)Wsrc[(size_t)(k8 + j) * F + col];
    *(half8*)(Wt + (size_t)m * F * F + (size_t)col * F + k8) = o;
}

// ============ aggregate: z0h[n] = hh[n] + sum_{j in adj(n)} hh[src_j] ============
__global__ __launch_bounds__(256) void k_agg(const _Float16* __restrict__ hh,
                                             const int* __restrict__ rowptr,
                                             const int* __restrict__ esrc,
                                             _Float16* __restrict__ z0h, int N)
{
    int n = (blockIdx.x * 256 + threadIdx.x) >> 6;
    if (n >= N) return;
    n = __builtin_amdgcn_readfirstlane(n);        // wave-uniform -> scalar loads
    const int lane = threadIdx.x & 63;
    const int beg = rowptr[n], end = rowptr[n + 1];
    const half2v* h2 = (const half2v*)hh;

    half2v v0 = h2[(size_t)n * 64 + lane];
    float ax = (float)v0.x, ay = (float)v0.y;
    float bx = 0.f, by = 0.f;
    int j = beg;
    for (; j + 2 <= end; j += 2) {
        int s0 = esrc[j], s1 = esrc[j + 1];
        half2v u0 = h2[(size_t)s0 * 64 + lane];
        half2v u1 = h2[(size_t)s1 * 64 + lane];
        ax += (float)u0.x; ay += (float)u0.y;
        bx += (float)u1.x; by += (float)u1.y;
    }
    if (j < end) {
        half2v u = h2[(size_t)esrc[j] * 64 + lane];
        ax += (float)u.x; ay += (float)u.y;
    }
    half2v o;
    o.x = (_Float16)(ax + bx);
    o.y = (_Float16)(ay + by);
    ((half2v*)z0h)[(size_t)n * 64 + lane] = o;
}

// ======== MFMA GEMM: Ch = relu(A @ W + bias), fp16 in/out, fp32 accum ========
// A fp16 [N][128]; Wt fp16 [col][k]; 128x128 tile, 4 waves 2x2, 4x4 MFMA/wave.
// Staging = pure b128 copies (weights pre-transposed+converted).
__global__ __launch_bounds__(256, 3) void k_gemm_mfma(
    const _Float16* __restrict__ A, const _Float16* __restrict__ Wt,
    const float* __restrict__ bias, _Float16* __restrict__ Ch,
    int N, float* stats)
{
    __shared__ _Float16 Al[128 * WT_S];
    __shared__ _Float16 Wl[128 * WT_S];
    const int t = threadIdx.x;
    const int row0 = blockIdx.x << 7;
    const int wave = t >> 6, lane = t & 63;
    const int wr = wave >> 1, wc = wave & 1;
    const int lrow = lane & 15, quad = lane >> 4;

    f32x4 acc[4][4];
#pragma unroll
    for (int i = 0; i < 4; ++i)
#pragma unroll
        for (int j = 0; j < 4; ++j) acc[i][j] = (f32x4){0.f, 0.f, 0.f, 0.f};

    for (int kb = 0; kb < 2; ++kb) {
        if (kb) __syncthreads();
        // ---- stage A: 128 rows x 64 halves, 4 b128 per thread
#pragma unroll
        for (int i = 0; i < 4; ++i) {
            int idx = t + (i << 8);             // 0..1023
            int row = idx >> 3;
            int k8  = (idx & 7) << 3;
            int gr = row0 + row;
            half8 v = {0, 0, 0, 0, 0, 0, 0, 0};
            if (gr < N) v = *(const half8*)(A + (size_t)gr * F + (kb << 6) + k8);
            *(half8*)(Al + row * WT_S + k8) = v;
        }
        // ---- stage Wt: 128 cols x 64 halves, 4 b128 per thread
#pragma unroll
        for (int i = 0; i < 4; ++i) {
            int idx = t + (i << 8);
            int col = idx >> 3;
            int k8  = (idx & 7) << 3;
            half8 v = *(const half8*)(Wt + (size_t)col * F + (kb << 6) + k8);
            *(half8*)(Wl + col * WT_S + k8) = v;
        }
        __syncthreads();
        // ---- compute: 2 k-chunks of 32 per kb
#pragma unroll
        for (int kc = 0; kc < 2; ++kc) {
            half8 af[4], bfr[4];
#pragma unroll
            for (int i = 0; i < 4; ++i)
                af[i] = *(half8*)(Al + (wr * 64 + i * 16 + lrow) * WT_S + kc * 32 + quad * 8);
#pragma unroll
            for (int j = 0; j < 4; ++j)
                bfr[j] = *(half8*)(Wl + (wc * 64 + j * 16 + lrow) * WT_S + kc * 32 + quad * 8);
#pragma unroll
            for (int i = 0; i < 4; ++i)
#pragma unroll
                for (int j = 0; j < 4; ++j)
                    acc[i][j] = __builtin_amdgcn_mfma_f32_16x16x32_f16(
                        af[i], bfr[j], acc[i][j], 0, 0, 0);
        }
    }

    // ---- epilogue: bias + relu + fp16 store + (optional) fp32 BN-stats
    const int colbase = wc * 64 + lrow;
    float bv[4];
#pragma unroll
    for (int j = 0; j < 4; ++j) bv[j] = bias[colbase + j * 16];

    float s[4], q[4];
#pragma unroll
    for (int j = 0; j < 4; ++j) { s[j] = 0.f; q[j] = 0.f; }

#pragma unroll
    for (int i = 0; i < 4; ++i) {
#pragma unroll
        for (int r = 0; r < 4; ++r) {
            int gr = row0 + wr * 64 + i * 16 + quad * 4 + r;
            if (gr < N) {
#pragma unroll
                for (int j = 0; j < 4; ++j) {
                    float u = acc[i][j][r] + bv[j];
                    u = fmaxf(u, 0.f);
                    Ch[(size_t)gr * F + colbase + j * 16] = (_Float16)u;
                    s[j] += u; q[j] += u * u;
                }
            }
        }
    }

    if (stats) {
        __syncthreads();                 // all frag reads done; reuse Al
        float* cs = (float*)Al;
        float* cq = cs + F;
        if (t < F) { cs[t] = 0.f; cq[t] = 0.f; }
        __syncthreads();
#pragma unroll
        for (int j = 0; j < 4; ++j) {
            atomicAdd(&cs[colbase + j * 16], s[j]);
            atomicAdd(&cq[colbase + j * 16], q[j]);
        }
        __syncthreads();
        if (t < F) {
            atomicAdd(&stats[t],     cs[t]);
            atomicAdd(&stats[F + t], cq[t]);
        }
    }
}

__global__ void k_bn_coef(const float* __restrict__ stats,
                          const float* __restrict__ gamma,
                          const float* __restrict__ beta,
                          float invN, float* __restrict__ coef)
{
    int f = threadIdx.x;
    float mean = stats[f] * invN;
    float var  = stats[F + f] * invN - mean * mean;
    float a = gamma[f] * rsqrtf(var + BN_EPS);
    coef[f]     = a;
    coef[F + f] = beta[f] - mean * a;
}

// ---- BN apply + segmented pool (fp32 regs) + fp16 h-write for next layer ----
__global__ __launch_bounds__(256) void k_bn_pool2(
    const _Float16* __restrict__ zh, const float* __restrict__ coef,
    const int* __restrict__ gptr, float* __restrict__ outL,
    _Float16* __restrict__ hh)
{
    const int g = blockIdx.x;
    const int beg = gptr[g], end = gptr[g + 1];
    const int t = threadIdx.x;
    const int wave = t >> 6, lane = t & 63;

    float2 a = ((const float2*)coef)[lane];
    float2 c = ((const float2*)(coef + F))[lane];
    float2 acc = make_float2(0.f, 0.f);
    const half2v* z2 = (const half2v*)zh;
    half2v* h2 = (half2v*)hh;

    for (int n = beg + wave; n < end; n += 4) {
        half2v v = z2[(size_t)n * 64 + lane];
        float vx = fmaf((float)v.x, a.x, c.x);
        float vy = fmaf((float)v.y, a.y, c.y);
        half2v o;
        o.x = (_Float16)vx; o.y = (_Float16)vy;
        h2[(size_t)n * 64 + lane] = o;      // h for next layer
        acc.x += vx; acc.y += vy;
    }

    __shared__ float2 red[4][64];
    red[wave][lane] = acc;
    __syncthreads();
    if (wave == 0) {
        float2 r = red[0][lane];
        r.x += red[1][lane].x + red[2][lane].x + red[3][lane].x;
        r.y += red[1][lane].y + red[2][lane].y + red[3][lane].y;
        ((float2*)outL)[(size_t)g * 192 + lane] = r;   // out row stride 384 floats
    }
}

extern "C" void kernel_launch(void* const* d_in, const int* in_sizes, int n_in,
                              void* d_out, int out_size, void* d_ws, size_t ws_size,
                              hipStream_t stream)
{
    const float* x     = (const float*)d_in[0];
    const int*   ei    = (const int*)  d_in[1];
    const int*   batch = (const int*)  d_in[2];
    const float* W1    = (const float*)d_in[3];
    const float* b1    = (const float*)d_in[4];
    const float* W2    = (const float*)d_in[5];
    const float* b2    = (const float*)d_in[6];
    const float* gamma = (const float*)d_in[7];
    const float* beta  = (const float*)d_in[8];

    const int N = in_sizes[0] / F;      // 100000
    const int E = in_sizes[1] / 2;      // 1600000
    const int* src = ei;
    const int* dst = ei + E;
    float* out = (float*)d_out;

    const size_t NF = (size_t)N * F;
    _Float16* P0 = (_Float16*)d_ws;         // hh   (layer input)
    _Float16* P1 = P0 + NF;                 // z0h / zh
    _Float16* P2 = P1 + NF;                 // tbh
    _Float16* Wt = P2 + NF;                 // 6 * 128*128 fp16 (pre-transposed)
    float* stats = (float*)(Wt + 6 * F * F);// 768
    float* coef  = stats + 768;             // 768
    int*   deg    = (int*)(coef + 768);     // N
    int*   rowptr = deg + N;                // N+1
    int*   cursor = rowptr + N + 1;         // N
    int*   bsum   = cursor + N;             // 256
    int*   gptr   = bsum + 256;             // NG+1
    int*   esrc   = gptr + NG + 1;          // E

    hipMemsetAsync(stats, 0, 768 * sizeof(float), stream);
    hipMemsetAsync(deg, 0, (size_t)N * sizeof(int), stream);

    // ---- CSR build + graph segments + one-time conversions ----
    const int nblk = (N + 1023) / 1024;
    k_hist <<<(E + 255) / 256, 256, 0, stream>>>(dst, deg, E);
    k_scan1<<<nblk, 256, 0, stream>>>(deg, rowptr, bsum, N);
    k_scan2<<<1, 256, 0, stream>>>(bsum, nblk);
    k_scan3<<<nblk, 256, 0, stream>>>(rowptr, cursor, bsum, N, E);
    k_fill <<<(E + 255) / 256, 256, 0, stream>>>(src, dst, cursor, esrc, E);
    k_gptr <<<(NG + 256) / 256, 256, 0, stream>>>(batch, gptr, N);
    const long n8 = (long)(NF / 8);
    k_x2h  <<<(int)((n8 + 255) / 256), 256, 0, stream>>>(x, P0, n8);
    k_wconv<<<48, 256, 0, stream>>>(W1, W2, Wt);

    const float invN = 1.0f / (float)N;
    const int gemm_grid = (N + 127) / 128;
    const int agg_grid  = (int)(((size_t)N * 64 + 255) / 256);

    for (int L = 0; L < 3; ++L) {
        k_agg<<<agg_grid, 256, 0, stream>>>(P0, rowptr, esrc, P1, N);
        k_gemm_mfma<<<gemm_grid, 256, 0, stream>>>(P1, Wt + (size_t)L * F * F,
                                                   b1 + L * F, P2, N, nullptr);
        k_gemm_mfma<<<gemm_grid, 256, 0, stream>>>(P2, Wt + (size_t)(3 + L) * F * F,
                                                   b2 + L * F, P1, N, stats + L * 256);
        k_bn_coef<<<1, F, 0, stream>>>(stats + L * 256, gamma + L * F, beta + L * F,
                                       invN, coef + L * 256);
        k_bn_pool2<<<NG, 256, 0, stream>>>(P1, coef + L * 256, gptr, out + L * F, P0);
    }
}

// Round 7
// 633.667 us; speedup vs baseline: 14.9725x; 1.1731x over previous
//
#include <hip/hip_runtime.h>

#define F 128
#define BN_EPS 1e-5f
#define NG 512    // NUM_GRAPHS
#define WT_S 72   // f16 LDS row stride (64 k + 8 pad) -> b128 reads 2-way/free

typedef __attribute__((ext_vector_type(8))) _Float16 half8;
typedef __attribute__((ext_vector_type(2))) _Float16 half2v;
typedef __attribute__((ext_vector_type(4))) float f32x4;

// ============ bucketed CSR build: buckets of 1024 nodes, L2-local fills ============

// global bucket histogram (LDS-staged)
__global__ __launch_bounds__(256) void k_bhist(const int* __restrict__ dst,
                                               int* __restrict__ gbcnt, int E)
{
    __shared__ int cnt[256];
    const int t = threadIdx.x;
    cnt[t] = 0;
    __syncthreads();
    const int base = blockIdx.x * 4096;
#pragma unroll
    for (int i = 0; i < 16; ++i) {
        int e = base + t + i * 256;
        if (e < E) atomicAdd(&cnt[dst[e] >> 10], 1);
    }
    __syncthreads();
    if (cnt[t]) atomicAdd(&gbcnt[t], cnt[t]);
}

// exclusive scan of NB bucket counts -> gcur (mutable cursors) + gbase (stable)
__global__ void k_bscan(const int* __restrict__ gbcnt, int* __restrict__ gcur,
                        int* __restrict__ gbase, int NB)
{
    __shared__ int c[257];
    const int t = threadIdx.x;
    if (t < NB) c[t] = gbcnt[t];
    __syncthreads();
    if (t == 0) {
        int s = 0;
        for (int b = 0; b < NB; ++b) { int v = c[b]; c[b] = s; s += v; }
        c[NB] = s;
    }
    __syncthreads();
    if (t < NB) gcur[t] = c[t];
    if (t <= NB) gbase[t] = c[t];
}

// bin (src,dst) pairs by bucket; per-block contiguous runs -> coalesced L2 writes
__global__ __launch_bounds__(256) void k_bin(const int* __restrict__ src,
                                             const int* __restrict__ dst,
                                             int* __restrict__ gcur,
                                             int2* __restrict__ pairs, int E)
{
    __shared__ int cnt[256], bse[256], lcur[256];
    const int t = threadIdx.x;
    cnt[t] = 0;
    __syncthreads();
    const int base = blockIdx.x * 4096;
    int d[16];
#pragma unroll
    for (int i = 0; i < 16; ++i) {
        int e = base + t + i * 256;
        d[i] = (e < E) ? dst[e] : -1;
        if (d[i] >= 0) atomicAdd(&cnt[d[i] >> 10], 1);
    }
    __syncthreads();
    if (cnt[t]) bse[t] = atomicAdd(&gcur[t], cnt[t]);
    lcur[t] = 0;
    __syncthreads();
#pragma unroll
    for (int i = 0; i < 16; ++i) {
        int e = base + t + i * 256;
        if (e < E) {
            int b = d[i] >> 10;
            int r = atomicAdd(&lcur[b], 1);
            pairs[bse[b] + r] = make_int2(src[e], d[i]);
        }
    }
}

// one block per bucket: local deg hist -> scan -> rowptr + cursor-fill esrc
// (all scattered writes land in the bucket's ~64KB L2-resident window)
__global__ __launch_bounds__(256) void k_csr(const int2* __restrict__ pairs,
                                             const int* __restrict__ gbase,
                                             int* __restrict__ rowptr,
                                             int* __restrict__ esrc, int N)
{
    __shared__ int deg[1024];
    __shared__ int scn[256];
    const int b = blockIdx.x, t = threadIdx.x;
    const int pb = gbase[b], pe = gbase[b + 1];
    const int node0 = b << 10;
    for (int i = t; i < 1024; i += 256) deg[i] = 0;
    __syncthreads();
    for (int i = pb + t; i < pe; i += 256) atomicAdd(&deg[pairs[i].y & 1023], 1);
    __syncthreads();
    int s0 = deg[t * 4], s1 = deg[t * 4 + 1], s2 = deg[t * 4 + 2], s3 = deg[t * 4 + 3];
    int s = s0 + s1 + s2 + s3;
    scn[t] = s;
    __syncthreads();
    for (int off = 1; off < 256; off <<= 1) {
        int u = (t >= off) ? scn[t - off] : 0;
        __syncthreads();
        if (t >= off) scn[t] += u;
        __syncthreads();
    }
    int excl = scn[t] - s;
    int c0 = pb + excl, c1 = c0 + s0, c2 = c1 + s1, c3 = c2 + s2;
    __syncthreads();
    deg[t * 4] = c0; deg[t * 4 + 1] = c1; deg[t * 4 + 2] = c2; deg[t * 4 + 3] = c3;
    int n0 = node0 + t * 4;
    if (n0 + 3 < N) *(int4*)(rowptr + n0) = make_int4(c0, c1, c2, c3);
    else {
        int cc[4] = {c0, c1, c2, c3};
        for (int k = 0; k < 4; ++k) if (n0 + k < N) rowptr[n0 + k] = cc[k];
    }
    __syncthreads();
    for (int i = pb + t; i < pe; i += 256) {
        int2 p = pairs[i];
        int pos = atomicAdd(&deg[p.y & 1023], 1);
        esrc[pos] = p.x;
    }
    if (b == gridDim.x - 1 && t == 0) rowptr[N] = pe;
}

// graph segment pointers: batch is sorted; gptr[g] = lower_bound(batch, g)
__global__ __launch_bounds__(256) void k_gptr(const int* __restrict__ batch,
                                              int* __restrict__ gptr, int N)
{
    int g = blockIdx.x * 256 + threadIdx.x;
    if (g > NG) return;
    int lo = 0, hi = N;
    while (lo < hi) {
        int mid = (lo + hi) >> 1;
        if (batch[mid] < g) lo = mid + 1; else hi = mid;
    }
    gptr[g] = lo;
}

// ================= one-time fp16 conversions =================

__global__ __launch_bounds__(256) void k_x2h(const float* __restrict__ x,
                                             _Float16* __restrict__ hh, long n8)
{
    long i = (long)blockIdx.x * 256 + threadIdx.x;
    if (i >= n8) return;
    float4 a = *(const float4*)(x + i * 8);
    float4 b = *(const float4*)(x + i * 8 + 4);
    half8 o;
    o[0] = (_Float16)a.x; o[1] = (_Float16)a.y; o[2] = (_Float16)a.z; o[3] = (_Float16)a.w;
    o[4] = (_Float16)b.x; o[5] = (_Float16)b.y; o[6] = (_Float16)b.z; o[7] = (_Float16)b.w;
    *(half8*)(hh + i * 8) = o;
}

// W1,W2 (fp32 [3][128][128] = [k][col]) -> Wt (fp16 [6][128][128] = [col][k])
__global__ __launch_bounds__(256) void k_wconv(const float* __restrict__ W1,
                                               const float* __restrict__ W2,
                                               _Float16* __restrict__ Wt)
{
    int m = blockIdx.x >> 3, cg = blockIdx.x & 7;
    const float* Wsrc = (m < 3) ? (W1 + (size_t)m * F * F) : (W2 + (size_t)(m - 3) * F * F);
    int col = cg * 16 + (threadIdx.x >> 4);
    int k8  = (threadIdx.x & 15) * 8;
    half8 o;
#pragma unroll
    for (int j = 0; j < 8; ++j) o[j] = (_Float16)Wsrc[(size_t)(k8 + j) * F + col];
    *(half8*)(Wt + (size_t)m * F * F + (size_t)col * F + k8) = o;
}

// ============ aggregate: z0h[n] = hh[n] + sum_{j in adj(n)} hh[src_j] ============
__global__ __launch_bounds__(256) void k_agg(const _Float16* __restrict__ hh,
                                             const int* __restrict__ rowptr,
                                             const int* __restrict__ esrc,
                                             _Float16* __restrict__ z0h, int N)
{
    int n = (blockIdx.x * 256 + threadIdx.x) >> 6;
    if (n >= N) return;
    n = __builtin_amdgcn_readfirstlane(n);        // wave-uniform -> scalar loads
    const int lane = threadIdx.x & 63;
    const int beg = rowptr[n], end = rowptr[n + 1];
    const half2v* h2 = (const half2v*)hh;

    half2v v0 = h2[(size_t)n * 64 + lane];
    float ax = (float)v0.x, ay = (float)v0.y;
    float bx = 0.f, by = 0.f;
    int j = beg;
    for (; j + 2 <= end; j += 2) {
        int s0 = esrc[j], s1 = esrc[j + 1];
        half2v u0 = h2[(size_t)s0 * 64 + lane];
        half2v u1 = h2[(size_t)s1 * 64 + lane];
        ax += (float)u0.x; ay += (float)u0.y;
        bx += (float)u1.x; by += (float)u1.y;
    }
    if (j < end) {
        half2v u = h2[(size_t)esrc[j] * 64 + lane];
        ax += (float)u.x; ay += (float)u.y;
    }
    half2v o;
    o.x = (_Float16)(ax + bx);
    o.y = (_Float16)(ay + by);
    ((half2v*)z0h)[(size_t)n * 64 + lane] = o;
}

// ======== MFMA GEMM: Ch = relu(A @ W + bias), fp16 in/out, fp32 accum ========
__global__ __launch_bounds__(256, 3) void k_gemm_mfma(
    const _Float16* __restrict__ A, const _Float16* __restrict__ Wt,
    const float* __restrict__ bias, _Float16* __restrict__ Ch,
    int N, float* stats)
{
    __shared__ _Float16 Al[128 * WT_S];
    __shared__ _Float16 Wl[128 * WT_S];
    const int t = threadIdx.x;
    const int row0 = blockIdx.x << 7;
    const int wave = t >> 6, lane = t & 63;
    const int wr = wave >> 1, wc = wave & 1;
    const int lrow = lane & 15, quad = lane >> 4;

    f32x4 acc[4][4];
#pragma unroll
    for (int i = 0; i < 4; ++i)
#pragma unroll
        for (int j = 0; j < 4; ++j) acc[i][j] = (f32x4){0.f, 0.f, 0.f, 0.f};

    for (int kb = 0; kb < 2; ++kb) {
        if (kb) __syncthreads();
#pragma unroll
        for (int i = 0; i < 4; ++i) {
            int idx = t + (i << 8);
            int row = idx >> 3;
            int k8  = (idx & 7) << 3;
            int gr = row0 + row;
            half8 v = {0, 0, 0, 0, 0, 0, 0, 0};
            if (gr < N) v = *(const half8*)(A + (size_t)gr * F + (kb << 6) + k8);
            *(half8*)(Al + row * WT_S + k8) = v;
        }
#pragma unroll
        for (int i = 0; i < 4; ++i) {
            int idx = t + (i << 8);
            int col = idx >> 3;
            int k8  = (idx & 7) << 3;
            half8 v = *(const half8*)(Wt + (size_t)col * F + (kb << 6) + k8);
            *(half8*)(Wl + col * WT_S + k8) = v;
        }
        __syncthreads();
#pragma unroll
        for (int kc = 0; kc < 2; ++kc) {
            half8 af[4], bfr[4];
#pragma unroll
            for (int i = 0; i < 4; ++i)
                af[i] = *(half8*)(Al + (wr * 64 + i * 16 + lrow) * WT_S + kc * 32 + quad * 8);
#pragma unroll
            for (int j = 0; j < 4; ++j)
                bfr[j] = *(half8*)(Wl + (wc * 64 + j * 16 + lrow) * WT_S + kc * 32 + quad * 8);
#pragma unroll
            for (int i = 0; i < 4; ++i)
#pragma unroll
                for (int j = 0; j < 4; ++j)
                    acc[i][j] = __builtin_amdgcn_mfma_f32_16x16x32_f16(
                        af[i], bfr[j], acc[i][j], 0, 0, 0);
        }
    }

    const int colbase = wc * 64 + lrow;
    float bv[4];
#pragma unroll
    for (int j = 0; j < 4; ++j) bv[j] = bias[colbase + j * 16];

    float s[4], q[4];
#pragma unroll
    for (int j = 0; j < 4; ++j) { s[j] = 0.f; q[j] = 0.f; }

#pragma unroll
    for (int i = 0; i < 4; ++i) {
#pragma unroll
        for (int r = 0; r < 4; ++r) {
            int gr = row0 + wr * 64 + i * 16 + quad * 4 + r;
            if (gr < N) {
#pragma unroll
                for (int j = 0; j < 4; ++j) {
                    float u = acc[i][j][r] + bv[j];
                    u = fmaxf(u, 0.f);
                    Ch[(size_t)gr * F + colbase + j * 16] = (_Float16)u;
                    s[j] += u; q[j] += u * u;
                }
            }
        }
    }

    if (stats) {
        __syncthreads();
        float* cs = (float*)Al;
        float* cq = cs + F;
        if (t < F) { cs[t] = 0.f; cq[t] = 0.f; }
        __syncthreads();
#pragma unroll
        for (int j = 0; j < 4; ++j) {
            atomicAdd(&cs[colbase + j * 16], s[j]);
            atomicAdd(&cq[colbase + j * 16], q[j]);
        }
        __syncthreads();
        if (t < F) {
            atomicAdd(&stats[t],     cs[t]);
            atomicAdd(&stats[F + t], cq[t]);
        }
    }
}

// ---- BN coef (in-block) + BN apply + segmented pool + fp16 h for next layer ----
__global__ __launch_bounds__(256) void k_bn_pool2(
    const _Float16* __restrict__ zh, const float* __restrict__ stats,
    const float* __restrict__ gamma, const float* __restrict__ beta, float invN,
    const int* __restrict__ gptr, float* __restrict__ outL,
    _Float16* __restrict__ hh)
{
    __shared__ float coefs[256];        // [0:128]=a, [128:256]=c
    const int g = blockIdx.x;
    const int t = threadIdx.x;
    if (t < F) {
        float mean = stats[t] * invN;
        float var  = stats[F + t] * invN - mean * mean;
        float a = gamma[t] * rsqrtf(var + BN_EPS);
        coefs[t]     = a;
        coefs[F + t] = beta[t] - mean * a;
    }
    __syncthreads();

    const int beg = gptr[g], end = gptr[g + 1];
    const int wave = t >> 6, lane = t & 63;

    float2 a = ((const float2*)coefs)[lane];
    float2 c = ((const float2*)(coefs + F))[lane];
    float2 acc = make_float2(0.f, 0.f);
    const half2v* z2 = (const half2v*)zh;
    half2v* h2 = (half2v*)hh;

    for (int n = beg + wave; n < end; n += 4) {
        half2v v = z2[(size_t)n * 64 + lane];
        float vx = fmaf((float)v.x, a.x, c.x);
        float vy = fmaf((float)v.y, a.y, c.y);
        half2v o;
        o.x = (_Float16)vx; o.y = (_Float16)vy;
        h2[(size_t)n * 64 + lane] = o;
        acc.x += vx; acc.y += vy;
    }

    __shared__ float2 red[4][64];
    red[wave][lane] = acc;
    __syncthreads();
    if (wave == 0) {
        float2 r = red[0][lane];
        r.x += red[1][lane].x + red[2][lane].x + red[3][lane].x;
        r.y += red[1][lane].y + red[2][lane].y + red[3][lane].y;
        ((float2*)outL)[(size_t)g * 192 + lane] = r;
    }
}

extern "C" void kernel_launch(void* const* d_in, const int* in_sizes, int n_in,
                              void* d_out, int out_size, void* d_ws, size_t ws_size,
                              hipStream_t stream)
{
    const float* x     = (const float*)d_in[0];
    const int*   ei    = (const int*)  d_in[1];
    const int*   batch = (const int*)  d_in[2];
    const float* W1    = (const float*)d_in[3];
    const float* b1    = (const float*)d_in[4];
    const float* W2    = (const float*)d_in[5];
    const float* b2    = (const float*)d_in[6];
    const float* gamma = (const float*)d_in[7];
    const float* beta  = (const float*)d_in[8];

    const int N = in_sizes[0] / F;      // 100000
    const int E = in_sizes[1] / 2;      // 1600000
    const int* src = ei;
    const int* dst = ei + E;
    float* out = (float*)d_out;

    const size_t NF = (size_t)N * F;
    _Float16* P0 = (_Float16*)d_ws;             // hh
    _Float16* P1 = P0 + NF;                     // z0h / zh
    _Float16* P2 = P1 + NF;                     // tbh
    _Float16* Wt = P2 + NF;                     // 6*F*F fp16
    float* stats  = (float*)(Wt + 6 * F * F);   // 768
    int*   gbcnt  = (int*)(stats + 768);        // 256  (memset with stats)
    int2*  pairs  = (int2*)(gbcnt + 256);       // E    (8B-aligned by layout)
    int*   esrc   = (int*)(pairs + E);          // E
    int*   rowptr = esrc + E;                   // N+1
    int*   gptr   = rowptr + N + 1;             // NG+1
    int*   gcur   = gptr + NG + 1;              // 256
    int*   gbase  = gcur + 256;                 // 257

    hipMemsetAsync(stats, 0, (768 + 256) * sizeof(float), stream);

    const int NB = (N + 1023) >> 10;            // 98 buckets of 1024 nodes
    const int ebk = (E + 4095) / 4096;

    // ---- bucketed CSR build + graph segments + fp16 conversions ----
    k_bhist<<<ebk, 256, 0, stream>>>(dst, gbcnt, E);
    k_bscan<<<1, 256, 0, stream>>>(gbcnt, gcur, gbase, NB);
    k_bin  <<<ebk, 256, 0, stream>>>(src, dst, gcur, pairs, E);
    k_csr  <<<NB, 256, 0, stream>>>(pairs, gbase, rowptr, esrc, N);
    k_gptr <<<(NG + 256) / 256, 256, 0, stream>>>(batch, gptr, N);
    const long n8 = (long)(NF / 8);
    k_x2h  <<<(int)((n8 + 255) / 256), 256, 0, stream>>>(x, P0, n8);
    k_wconv<<<48, 256, 0, stream>>>(W1, W2, Wt);

    const float invN = 1.0f / (float)N;
    const int gemm_grid = (N + 127) / 128;
    const int agg_grid  = (int)(((size_t)N * 64 + 255) / 256);

    for (int L = 0; L < 3; ++L) {
        k_agg<<<agg_grid, 256, 0, stream>>>(P0, rowptr, esrc, P1, N);
        k_gemm_mfma<<<gemm_grid, 256, 0, stream>>>(P1, Wt + (size_t)L * F * F,
                                                   b1 + L * F, P2, N, nullptr);
        k_gemm_mfma<<<gemm_grid, 256, 0, stream>>>(P2, Wt + (size_t)(3 + L) * F * F,
                                                   b2 + L * F, P1, N, stats + L * 256);
        k_bn_pool2<<<NG, 256, 0, stream>>>(P1, stats + L * 256, gamma + L * F,
                                           beta + L * F, invN, gptr, out + L * F, P0);
    }
}

// Round 8
// 574.128 us; speedup vs baseline: 16.5252x; 1.1037x over previous
//
#include <hip/hip_runtime.h>

#define F 128
#define BN_EPS 1e-5f
#define NG 512    // NUM_GRAPHS
#define WT_S 72   // W LDS stride (64 k + 8 pad)
#define AL_S 136  // A/t LDS stride (128 k + 8 pad)

typedef __attribute__((ext_vector_type(8))) _Float16 half8;
typedef __attribute__((ext_vector_type(2))) _Float16 half2v;
typedef __attribute__((ext_vector_type(4))) float f32x4;

// ============ bucketed CSR build: buckets of 1024 nodes, L2-local fills ============

__global__ __launch_bounds__(256) void k_bhist(const int* __restrict__ dst,
                                               int* __restrict__ gbcnt, int E)
{
    __shared__ int cnt[256];
    const int t = threadIdx.x;
    cnt[t] = 0;
    __syncthreads();
    const int base = blockIdx.x * 4096;
#pragma unroll
    for (int i = 0; i < 16; ++i) {
        int e = base + t + i * 256;
        if (e < E) atomicAdd(&cnt[dst[e] >> 10], 1);
    }
    __syncthreads();
    if (cnt[t]) atomicAdd(&gbcnt[t], cnt[t]);
}

__global__ void k_bscan(const int* __restrict__ gbcnt, int* __restrict__ gcur,
                        int* __restrict__ gbase, int NB)
{
    __shared__ int c[257];
    const int t = threadIdx.x;
    if (t < NB) c[t] = gbcnt[t];
    __syncthreads();
    if (t == 0) {
        int s = 0;
        for (int b = 0; b < NB; ++b) { int v = c[b]; c[b] = s; s += v; }
        c[NB] = s;
    }
    __syncthreads();
    if (t < NB) gcur[t] = c[t];
    if (t <= NB) gbase[t] = c[t];
}

__global__ __launch_bounds__(256) void k_bin(const int* __restrict__ src,
                                             const int* __restrict__ dst,
                                             int* __restrict__ gcur,
                                             int2* __restrict__ pairs, int E)
{
    __shared__ int cnt[256], bse[256], lcur[256];
    const int t = threadIdx.x;
    cnt[t] = 0;
    __syncthreads();
    const int base = blockIdx.x * 4096;
    int d[16];
#pragma unroll
    for (int i = 0; i < 16; ++i) {
        int e = base + t + i * 256;
        d[i] = (e < E) ? dst[e] : -1;
        if (d[i] >= 0) atomicAdd(&cnt[d[i] >> 10], 1);
    }
    __syncthreads();
    if (cnt[t]) bse[t] = atomicAdd(&gcur[t], cnt[t]);
    lcur[t] = 0;
    __syncthreads();
#pragma unroll
    for (int i = 0; i < 16; ++i) {
        int e = base + t + i * 256;
        if (e < E) {
            int b = d[i] >> 10;
            int r = atomicAdd(&lcur[b], 1);
            pairs[bse[b] + r] = make_int2(src[e], d[i]);
        }
    }
}

__global__ __launch_bounds__(256) void k_csr(const int2* __restrict__ pairs,
                                             const int* __restrict__ gbase,
                                             int* __restrict__ rowptr,
                                             int* __restrict__ esrc, int N)
{
    __shared__ int deg[1024];
    __shared__ int scn[256];
    const int b = blockIdx.x, t = threadIdx.x;
    const int pb = gbase[b], pe = gbase[b + 1];
    const int node0 = b << 10;
    for (int i = t; i < 1024; i += 256) deg[i] = 0;
    __syncthreads();
    for (int i = pb + t; i < pe; i += 256) atomicAdd(&deg[pairs[i].y & 1023], 1);
    __syncthreads();
    int s0 = deg[t * 4], s1 = deg[t * 4 + 1], s2 = deg[t * 4 + 2], s3 = deg[t * 4 + 3];
    int s = s0 + s1 + s2 + s3;
    scn[t] = s;
    __syncthreads();
    for (int off = 1; off < 256; off <<= 1) {
        int u = (t >= off) ? scn[t - off] : 0;
        __syncthreads();
        if (t >= off) scn[t] += u;
        __syncthreads();
    }
    int excl = scn[t] - s;
    int c0 = pb + excl, c1 = c0 + s0, c2 = c1 + s1, c3 = c2 + s2;
    __syncthreads();
    deg[t * 4] = c0; deg[t * 4 + 1] = c1; deg[t * 4 + 2] = c2; deg[t * 4 + 3] = c3;
    int n0 = node0 + t * 4;
    if (n0 + 3 < N) *(int4*)(rowptr + n0) = make_int4(c0, c1, c2, c3);
    else {
        int cc[4] = {c0, c1, c2, c3};
        for (int k = 0; k < 4; ++k) if (n0 + k < N) rowptr[n0 + k] = cc[k];
    }
    __syncthreads();
    for (int i = pb + t; i < pe; i += 256) {
        int2 p = pairs[i];
        int pos = atomicAdd(&deg[p.y & 1023], 1);
        esrc[pos] = p.x;
    }
    if (b == gridDim.x - 1 && t == 0) rowptr[N] = pe;
}

__global__ __launch_bounds__(256) void k_gptr(const int* __restrict__ batch,
                                              int* __restrict__ gptr, int N)
{
    int g = blockIdx.x * 256 + threadIdx.x;
    if (g > NG) return;
    int lo = 0, hi = N;
    while (lo < hi) {
        int mid = (lo + hi) >> 1;
        if (batch[mid] < g) lo = mid + 1; else hi = mid;
    }
    gptr[g] = lo;
}

// ================= one-time fp16 conversions =================

__global__ __launch_bounds__(256) void k_x2h(const float* __restrict__ x,
                                             _Float16* __restrict__ hh, long n8)
{
    long i = (long)blockIdx.x * 256 + threadIdx.x;
    if (i >= n8) return;
    float4 a = *(const float4*)(x + i * 8);
    float4 b = *(const float4*)(x + i * 8 + 4);
    half8 o;
    o[0] = (_Float16)a.x; o[1] = (_Float16)a.y; o[2] = (_Float16)a.z; o[3] = (_Float16)a.w;
    o[4] = (_Float16)b.x; o[5] = (_Float16)b.y; o[6] = (_Float16)b.z; o[7] = (_Float16)b.w;
    *(half8*)(hh + i * 8) = o;
}

__global__ __launch_bounds__(256) void k_wconv(const float* __restrict__ W1,
                                               const float* __restrict__ W2,
                                               _Float16* __restrict__ Wt)
{
    int m = blockIdx.x >> 3, cg = blockIdx.x & 7;
    const float* Wsrc = (m < 3) ? (W1 + (size_t)m * F * F) : (W2 + (size_t)(m - 3) * F * F);
    int col = cg * 16 + (threadIdx.x >> 4);
    int k8  = (threadIdx.x & 15) * 8;
    half8 o;
#pragma unroll
    for (int j = 0; j < 8; ++j) o[j] = (_Float16)Wsrc[(size_t)(k8 + j) * F + col];
    *(half8*)(Wt + (size_t)m * F * F + (size_t)col * F + k8) = o;
}

// ===== aggregate: z0h[n] = hh[n] + sum h[src]; 16 lanes/node, b128 gathers =====
__global__ __launch_bounds__(256) void k_agg2(const _Float16* __restrict__ hh,
                                              const int* __restrict__ rowptr,
                                              const int* __restrict__ esrc,
                                              _Float16* __restrict__ z0h, int N)
{
    int n = blockIdx.x * 16 + (threadIdx.x >> 4);
    if (n >= N) return;
    const int l16 = threadIdx.x & 15;
    const half8* h8 = (const half8*)hh;
    const int beg = rowptr[n], end = rowptr[n + 1];

    half8 v = h8[(size_t)n * 16 + l16];
    float a[8], b[8];
#pragma unroll
    for (int k = 0; k < 8; ++k) { a[k] = (float)v[k]; b[k] = 0.f; }

    int j = beg;
    for (; j + 2 <= end; j += 2) {
        int s0 = esrc[j], s1 = esrc[j + 1];
        half8 u0 = h8[(size_t)s0 * 16 + l16];
        half8 u1 = h8[(size_t)s1 * 16 + l16];
#pragma unroll
        for (int k = 0; k < 8; ++k) { a[k] += (float)u0[k]; b[k] += (float)u1[k]; }
    }
    if (j < end) {
        half8 u = h8[(size_t)esrc[j] * 16 + l16];
#pragma unroll
        for (int k = 0; k < 8; ++k) a[k] += (float)u[k];
    }
    half8 o;
#pragma unroll
    for (int k = 0; k < 8; ++k) o[k] = (_Float16)(a[k] + b[k]);
    ((half8*)z0h)[(size_t)n * 16 + l16] = o;
}

// ===== fused MLP: Z <- relu(relu(Z@W1+b1)@W2+b2), in-place, + BN stats =====
// 128 rows/block, 256 thr (2x2 waves of 64x64). t-tile round-trips through Al.
__global__ __launch_bounds__(256, 3) void k_mlp(
    _Float16* __restrict__ Z,
    const _Float16* __restrict__ W1t, const float* __restrict__ b1,
    const _Float16* __restrict__ W2t, const float* __restrict__ b2,
    int N, float* __restrict__ stats)
{
    __shared__ _Float16 Al[128 * AL_S];
    __shared__ _Float16 Wl[128 * WT_S];
    const int t = threadIdx.x;
    const int row0 = blockIdx.x << 7;
    const int wave = t >> 6, lane = t & 63;
    const int wr = wave >> 1, wc = wave & 1;
    const int lrow = lane & 15, quad = lane >> 4;
    const int colbase = wc * 64 + lrow;

    // ---- stage A (full K = 128)
#pragma unroll
    for (int i = 0; i < 8; ++i) {
        int idx = t + (i << 8);        // 0..2047
        int row = idx >> 4;
        int k8  = (idx & 15) << 3;
        int gr = row0 + row;
        half8 v = {0, 0, 0, 0, 0, 0, 0, 0};
        if (gr < N) v = *(const half8*)(Z + (size_t)gr * F + k8);
        *(half8*)(Al + row * AL_S + k8) = v;
    }

    f32x4 acc[4][4];
#pragma unroll
    for (int i = 0; i < 4; ++i)
#pragma unroll
        for (int j = 0; j < 4; ++j) acc[i][j] = (f32x4){0.f, 0.f, 0.f, 0.f};

    // ---- GEMM1
    for (int kb = 0; kb < 2; ++kb) {
        __syncthreads();
#pragma unroll
        for (int i = 0; i < 4; ++i) {
            int idx = t + (i << 8);
            int col = idx >> 3;
            int k8  = (idx & 7) << 3;
            *(half8*)(Wl + col * WT_S + k8) =
                *(const half8*)(W1t + (size_t)col * F + (kb << 6) + k8);
        }
        __syncthreads();
#pragma unroll
        for (int kc = 0; kc < 2; ++kc) {
            half8 af[4], bfr[4];
#pragma unroll
            for (int i = 0; i < 4; ++i)
                af[i] = *(half8*)(Al + (wr * 64 + i * 16 + lrow) * AL_S + (kb << 6) + kc * 32 + quad * 8);
#pragma unroll
            for (int j = 0; j < 4; ++j)
                bfr[j] = *(half8*)(Wl + (wc * 64 + j * 16 + lrow) * WT_S + kc * 32 + quad * 8);
#pragma unroll
            for (int i = 0; i < 4; ++i)
#pragma unroll
                for (int j = 0; j < 4; ++j)
                    acc[i][j] = __builtin_amdgcn_mfma_f32_16x16x32_f16(
                        af[i], bfr[j], acc[i][j], 0, 0, 0);
        }
    }

    // ---- t = relu(acc + b1) -> Al (barrier: all GEMM1 reads done)
    float bv[4];
#pragma unroll
    for (int j = 0; j < 4; ++j) bv[j] = b1[colbase + j * 16];
    __syncthreads();
#pragma unroll
    for (int i = 0; i < 4; ++i)
#pragma unroll
        for (int r = 0; r < 4; ++r) {
            int row = wr * 64 + i * 16 + quad * 4 + r;
#pragma unroll
            for (int j = 0; j < 4; ++j)
                Al[row * AL_S + colbase + j * 16] =
                    (_Float16)fmaxf(acc[i][j][r] + bv[j], 0.f);
        }

#pragma unroll
    for (int i = 0; i < 4; ++i)
#pragma unroll
        for (int j = 0; j < 4; ++j) acc[i][j] = (f32x4){0.f, 0.f, 0.f, 0.f};

    // ---- GEMM2
    for (int kb = 0; kb < 2; ++kb) {
        __syncthreads();
#pragma unroll
        for (int i = 0; i < 4; ++i) {
            int idx = t + (i << 8);
            int col = idx >> 3;
            int k8  = (idx & 7) << 3;
            *(half8*)(Wl + col * WT_S + k8) =
                *(const half8*)(W2t + (size_t)col * F + (kb << 6) + k8);
        }
        __syncthreads();
#pragma unroll
        for (int kc = 0; kc < 2; ++kc) {
            half8 af[4], bfr[4];
#pragma unroll
            for (int i = 0; i < 4; ++i)
                af[i] = *(half8*)(Al + (wr * 64 + i * 16 + lrow) * AL_S + (kb << 6) + kc * 32 + quad * 8);
#pragma unroll
            for (int j = 0; j < 4; ++j)
                bfr[j] = *(half8*)(Wl + (wc * 64 + j * 16 + lrow) * WT_S + kc * 32 + quad * 8);
#pragma unroll
            for (int i = 0; i < 4; ++i)
#pragma unroll
                for (int j = 0; j < 4; ++j)
                    acc[i][j] = __builtin_amdgcn_mfma_f32_16x16x32_f16(
                        af[i], bfr[j], acc[i][j], 0, 0, 0);
        }
    }

    // ---- epilogue: z = relu(acc + b2); stats (fp32); z -> Al -> coalesced store
#pragma unroll
    for (int j = 0; j < 4; ++j) bv[j] = b2[colbase + j * 16];

    float s[4], q[4];
#pragma unroll
    for (int j = 0; j < 4; ++j) { s[j] = 0.f; q[j] = 0.f; }

    __syncthreads();                     // all GEMM2 reads of Al/Wl done
    float* cs = (float*)Wl;
    float* cq = cs + F;
    if (t < F) { cs[t] = 0.f; cq[t] = 0.f; }
#pragma unroll
    for (int i = 0; i < 4; ++i)
#pragma unroll
        for (int r = 0; r < 4; ++r) {
            int row = wr * 64 + i * 16 + quad * 4 + r;
            bool ok = (row0 + row) < N;
#pragma unroll
            for (int j = 0; j < 4; ++j) {
                float u = fmaxf(acc[i][j][r] + bv[j], 0.f);
                Al[row * AL_S + colbase + j * 16] = (_Float16)u;
                if (ok) { s[j] += u; q[j] += u * u; }
            }
        }
    __syncthreads();                     // Al z-tile + cs/cq init complete
#pragma unroll
    for (int j = 0; j < 4; ++j) {
        atomicAdd(&cs[colbase + j * 16], s[j]);
        atomicAdd(&cq[colbase + j * 16], q[j]);
    }
#pragma unroll
    for (int i = 0; i < 8; ++i) {        // coalesced b128 store of z
        int idx = t + (i << 8);
        int row = idx >> 4;
        int k8  = (idx & 15) << 3;
        int gr = row0 + row;
        if (gr < N)
            *(half8*)(Z + (size_t)gr * F + k8) = *(half8*)(Al + row * AL_S + k8);
    }
    __syncthreads();                     // cs/cq atomics complete
    if (t < F) {
        atomicAdd(&stats[t],     cs[t]);
        atomicAdd(&stats[F + t], cq[t]);
    }
}

// ---- BN coef (in-block) + BN apply + segmented pool + fp16 h for next layer ----
__global__ __launch_bounds__(256) void k_bn_pool2(
    const _Float16* __restrict__ zh, const float* __restrict__ stats,
    const float* __restrict__ gamma, const float* __restrict__ beta, float invN,
    const int* __restrict__ gptr, float* __restrict__ outL,
    _Float16* __restrict__ hh)
{
    __shared__ float coefs[256];
    const int g = blockIdx.x;
    const int t = threadIdx.x;
    if (t < F) {
        float mean = stats[t] * invN;
        float var  = stats[F + t] * invN - mean * mean;
        float a = gamma[t] * rsqrtf(var + BN_EPS);
        coefs[t]     = a;
        coefs[F + t] = beta[t] - mean * a;
    }
    __syncthreads();

    const int beg = gptr[g], end = gptr[g + 1];
    const int wave = t >> 6, lane = t & 63;

    float2 a = ((const float2*)coefs)[lane];
    float2 c = ((const float2*)(coefs + F))[lane];
    float2 acc = make_float2(0.f, 0.f);
    const half2v* z2 = (const half2v*)zh;
    half2v* h2 = (half2v*)hh;

    for (int n = beg + wave; n < end; n += 4) {
        half2v v = z2[(size_t)n * 64 + lane];
        float vx = fmaf((float)v.x, a.x, c.x);
        float vy = fmaf((float)v.y, a.y, c.y);
        half2v o;
        o.x = (_Float16)vx; o.y = (_Float16)vy;
        h2[(size_t)n * 64 + lane] = o;
        acc.x += vx; acc.y += vy;
    }

    __shared__ float2 red[4][64];
    red[wave][lane] = acc;
    __syncthreads();
    if (wave == 0) {
        float2 r = red[0][lane];
        r.x += red[1][lane].x + red[2][lane].x + red[3][lane].x;
        r.y += red[1][lane].y + red[2][lane].y + red[3][lane].y;
        ((float2*)outL)[(size_t)g * 192 + lane] = r;
    }
}

extern "C" void kernel_launch(void* const* d_in, const int* in_sizes, int n_in,
                              void* d_out, int out_size, void* d_ws, size_t ws_size,
                              hipStream_t stream)
{
    const float* x     = (const float*)d_in[0];
    const int*   ei    = (const int*)  d_in[1];
    const int*   batch = (const int*)  d_in[2];
    const float* W1    = (const float*)d_in[3];
    const float* b1    = (const float*)d_in[4];
    const float* W2    = (const float*)d_in[5];
    const float* b2    = (const float*)d_in[6];
    const float* gamma = (const float*)d_in[7];
    const float* beta  = (const float*)d_in[8];

    const int N = in_sizes[0] / F;      // 100000
    const int E = in_sizes[1] / 2;      // 1600000
    const int* src = ei;
    const int* dst = ei + E;
    float* out = (float*)d_out;

    const size_t NF = (size_t)N * F;
    _Float16* P0 = (_Float16*)d_ws;             // hh
    _Float16* P1 = P0 + NF;                     // z0 / z (in-place MLP)
    _Float16* Wt = P1 + NF;                     // 6*F*F fp16
    float* stats  = (float*)(Wt + 6 * F * F);   // 768
    int*   gbcnt  = (int*)(stats + 768);        // 256
    int2*  pairs  = (int2*)(gbcnt + 256);       // E
    int*   esrc   = (int*)(pairs + E);          // E
    int*   rowptr = esrc + E;                   // N+1
    int*   gptr   = rowptr + N + 1;             // NG+1
    int*   gcur   = gptr + NG + 1;              // 256
    int*   gbase  = gcur + 256;                 // 257

    hipMemsetAsync(stats, 0, (768 + 256) * sizeof(float), stream);

    const int NB = (N + 1023) >> 10;
    const int ebk = (E + 4095) / 4096;

    k_bhist<<<ebk, 256, 0, stream>>>(dst, gbcnt, E);
    k_bscan<<<1, 256, 0, stream>>>(gbcnt, gcur, gbase, NB);
    k_bin  <<<ebk, 256, 0, stream>>>(src, dst, gcur, pairs, E);
    k_csr  <<<NB, 256, 0, stream>>>(pairs, gbase, rowptr, esrc, N);
    k_gptr <<<(NG + 256) / 256, 256, 0, stream>>>(batch, gptr, N);
    const long n8 = (long)(NF / 8);
    k_x2h  <<<(int)((n8 + 255) / 256), 256, 0, stream>>>(x, P0, n8);
    k_wconv<<<48, 256, 0, stream>>>(W1, W2, Wt);

    const float invN = 1.0f / (float)N;
    const int mlp_grid = (N + 127) / 128;
    const int agg_grid = (N + 15) / 16;

    for (int L = 0; L < 3; ++L) {
        k_agg2<<<agg_grid, 256, 0, stream>>>(P0, rowptr, esrc, P1, N);
        k_mlp<<<mlp_grid, 256, 0, stream>>>(P1, Wt + (size_t)L * F * F, b1 + L * F,
                                            Wt + (size_t)(3 + L) * F * F, b2 + L * F,
                                            N, stats + L * 256);
        k_bn_pool2<<<NG, 256, 0, stream>>>(P1, stats + L * 256, gamma + L * F,
                                           beta + L * F, invN, gptr, out + L * F, P0);
    }
}